// Round 7
// baseline (748.509 us; speedup 1.0000x reference)
//
// CrossAttentionBlock_56813827392085 — fused transformer block, bf16 MFMA internals. R13:
//  = R12 structure + NO-LDS, NO-BARRIER GEMMs: both A and B operands stream directly
//  from global in MFMA-fragment layout (convw now emits W in frag layout; producers
//  already emit A in frag layout since R12). The K-loop is {8x global_load_dwordx4
//  prefetch -> 16 MFMA}, register-double-buffered, ZERO s_barrier/__syncthreads/LDS.
//  Rationale: MfmaUtil pinned ~21% across 6 rounds of loop variants; occupancy-doubling
//  null (R11) + LDS-halving small gain (R12) + nothing saturated => the per-K-step
//  barrier lockstep is the binding constraint. Removing barriers trades LDS broadcast
//  of B for L2 re-reads (~1GB/dispatch worst case ~= 30us at 34.5TB/s L2 — below the
//  current 62us). Epilogues, grids, ctx/apply/ln, QB/KB/VB row-major: unchanged.
#include <hip/hip_runtime.h>
#include <hip/hip_bf16.h>
#include <math.h>
#include <stdint.h>

typedef unsigned short u16;
typedef __attribute__((ext_vector_type(8))) short bh8;
typedef __attribute__((ext_vector_type(4))) float fx4;

#define DEV static __device__ __forceinline__

DEV float bf2f(u16 u){ union{unsigned u; float f;} v; v.u = ((unsigned)u)<<16; return v.f; }
DEV u16 f2bf(float f){ union{float f; unsigned u;} v; v.f = f;
  return (u16)((v.u + 0x7fffu + ((v.u>>16)&1u))>>16); }               // RNE

// MFMA fragment address within a [rows][Kbuf] bf16 matrix:
// elem(row,k) -> (row>>4)*16*Kbuf + (k>>3)*128 + (row&15)*8 + (k&7)
DEV size_t faddr(int row, int col, int Kbuf){
  return (size_t)(row>>4)*((size_t)Kbuf*16)
       + (size_t)((col>>3)*128 + (row&15)*8 + (col&7));
}

// gelu tanh-approx via sigmoid identity: x * 1/(1+exp(x*(-1.59577 - 0.0713548*x^2)))
DEV float gelu_fast(float x){
  float x2 = x*x;
  float t  = __builtin_fmaf(x2, -0.071354816f, -1.5957691216f);
  float e  = __expf(x*t);
  return __fdividef(x, 1.f + e);
}

// XCD-aware bijective block swizzle (requires nwg%8==0 — all GEMM grids here satisfy).
DEV int2 xcd_swz(){
  const int gx  = gridDim.x;
  const int ord = blockIdx.y*gx + blockIdx.x;
  const int nwg = gx*gridDim.y;
  const int wg  = (ord&7)*(nwg>>3) + (ord>>3);
  int2 r; r.x = wg % gx; r.y = wg / gx; return r;
}

// ---------------- weight fp32 -> bf16 pack, FRAGMENT layout ----------------
struct WDesc { const float* src[14]; int off[14]; int ksh[14]; };
__global__ __launch_bounds__(256) void convw_kernel(WDesc d, u16* __restrict__ dst){
  int i = blockIdx.x*256 + threadIdx.x;
  int s = 0;
  #pragma unroll
  for(int j=1;j<14;j++) if(i >= d.off[j]) s = j;
  int local = i - d.off[s];
  int ksh = d.ksh[s];
  int n = local >> ksh, k = local & ((1<<ksh)-1);
  dst[d.off[s] + faddr(n, k, 1<<ksh)] = f2bf(d.src[s][local]);
}

// ---------------- LayerNorm (C=512), fp32 in -> bf16 FRAGMENT-layout out ----------------
DEV float wsum64(float s){
  s += __shfl_xor(s,1,64);  s += __shfl_xor(s,2,64);  s += __shfl_xor(s,4,64);
  s += __shfl_xor(s,8,64);  s += __shfl_xor(s,16,64); s += __shfl_xor(s,32,64);
  return s;
}
DEV void ln_row(const float* xrow, const float* g, const float* bta, u16* orow, int lane){
  const float4* xr = (const float4*)xrow + lane*2;
  float4 a = xr[0], c = xr[1];
  float s = a.x+a.y+a.z+a.w + c.x+c.y+c.z+c.w;
  float mean = wsum64(s) * (1.f/512.f);
  float d0=a.x-mean,d1=a.y-mean,d2=a.z-mean,d3=a.w-mean;
  float d4=c.x-mean,d5=c.y-mean,d6=c.z-mean,d7=c.w-mean;
  float sv = d0*d0+d1*d1+d2*d2+d3*d3+d4*d4+d5*d5+d6*d6+d7*d7;
  float rstd = rsqrtf(wsum64(sv)*(1.f/512.f) + 1e-5f);
  const float4* gr = (const float4*)g   + lane*2;
  const float4* br = (const float4*)bta + lane*2;
  float4 g0=gr[0], g1=gr[1], b0=br[0], b1=br[1];
  bh8 o;
  o[0]=(short)f2bf(d0*rstd*g0.x+b0.x); o[1]=(short)f2bf(d1*rstd*g0.y+b0.y);
  o[2]=(short)f2bf(d2*rstd*g0.z+b0.z); o[3]=(short)f2bf(d3*rstd*g0.w+b0.w);
  o[4]=(short)f2bf(d4*rstd*g1.x+b1.x); o[5]=(short)f2bf(d5*rstd*g1.y+b1.y);
  o[6]=(short)f2bf(d6*rstd*g1.z+b1.z); o[7]=(short)f2bf(d7*rstd*g1.w+b1.w);
  *(bh8*)(orow + (size_t)lane*128) = o;
}
__global__ __launch_bounds__(256) void ln_kernel(const float* __restrict__ x,
    const float* __restrict__ g, const float* __restrict__ bta, u16* __restrict__ out){
  int row  = blockIdx.x*4 + (threadIdx.x>>6);
  u16* orow = out + (size_t)(row>>4)*8192 + (size_t)(row&15)*8;
  ln_row(x + (size_t)row*512, g, bta, orow, threadIdx.x&63);
}
__global__ __launch_bounds__(256) void lny_kernel(const float* __restrict__ ys,
    const float* __restrict__ g2, const float* __restrict__ b2, u16* __restrict__ out){
  int row  = blockIdx.x*4 + (threadIdx.x>>6);
  int i = row>>14;
  u16* orow = out + (size_t)(row>>4)*8192 + (size_t)(row&15)*8;
  ln_row(ys + (size_t)row*512, g2 + i*512, b2 + i*512, orow, threadIdx.x&63);
}

// ==== No-LDS GEMM K-loops: A and B both frag-layout in global, register dbuf. ====
// C/D layout: out_row = quad*4+r (within 16), out_col = l15.
#define PREF4(F, base, K, kk)                                                        \
    _Pragma("unroll")                                                                \
    for(int t=0;t<4;t++)                                                             \
      F[t] = *(const bh8*)((base) + (size_t)t*16*(K) + (size_t)(kk)*16);
#define PREF2(F, base, K, kk)                                                        \
    _Pragma("unroll")                                                                \
    for(int t=0;t<2;t++)                                                             \
      F[t] = *(const bh8*)((base) + (size_t)t*16*(K) + (size_t)(kk)*16);

#define MFMA_4x4(AF, BF)                                                             \
    _Pragma("unroll")                                                                \
    for(int mt=0;mt<4;mt++)                                                          \
      _Pragma("unroll")                                                              \
      for(int nt=0;nt<4;nt++)                                                        \
        acc[mt][nt] = __builtin_amdgcn_mfma_f32_16x16x32_bf16(AF[mt], BF[nt], acc[mt][nt], 0,0,0);
#define MFMA_2x4(AF, BF)                                                             \
    _Pragma("unroll")                                                                \
    for(int mt=0;mt<2;mt++)                                                          \
      _Pragma("unroll")                                                              \
      for(int nt=0;nt<4;nt++)                                                        \
        acc[mt][nt] = __builtin_amdgcn_mfma_f32_16x16x32_bf16(AF[mt], BF[nt], acc[mt][nt], 0,0,0);

// 128x128 block, 2x2 waves, wave tile 64x64 (A 4 frags, B 4 frags).
#define KLOOP128_RR(Ab, Wb, K)                                                       \
  const u16* Alane = (Ab) + (size_t)(wm*4)*16*(K) + lane*8;                          \
  const u16* Wlane = (Wb) + (size_t)(wn*4)*16*(K) + lane*8;                          \
  bh8 aA[4], bA[4], aB[4], bB[4];                                                    \
  PREF4(aA, Alane, K, 0) PREF4(bA, Wlane, K, 0)                                      \
  const int NS = (K)>>5;                                                             \
  for(int j=0;j<NS;j+=2){                                                            \
    if(j+1<NS){ PREF4(aB, Alane, K, (j+1)*32) PREF4(bB, Wlane, K, (j+1)*32) }        \
    MFMA_4x4(aA, bA)                                                                 \
    if(j+2<NS){ PREF4(aA, Alane, K, (j+2)*32) PREF4(bA, Wlane, K, (j+2)*32) }        \
    if(j+1<NS){ MFMA_4x4(aB, bB) }                                                   \
  }

// 128x64 block, 4 waves stacked in M, wave tile 32x64 (A 2 frags, B 4 frags shared cols).
#define KLOOP64_RR(Ab, Wb, K)                                                        \
  const u16* Alane = (Ab) + (size_t)(w*2)*16*(K) + lane*8;                           \
  const u16* Wlane = (Wb) + lane*8;                                                  \
  bh8 aA[2], bA[4], aB[2], bB[4];                                                    \
  PREF2(aA, Alane, K, 0) PREF4(bA, Wlane, K, 0)                                      \
  const int NS = (K)>>5;                                                             \
  for(int j=0;j<NS;j+=2){                                                            \
    if(j+1<NS){ PREF2(aB, Alane, K, (j+1)*32) PREF4(bB, Wlane, K, (j+1)*32) }        \
    MFMA_2x4(aA, bA)                                                                 \
    if(j+2<NS){ PREF2(aA, Alane, K, (j+2)*32) PREF4(bA, Wlane, K, (j+2)*32) }        \
    if(j+1<NS){ MFMA_2x4(aB, bB) }                                                   \
  }

// ---------------- multi-output projection GEMM (BN=128, no-LDS) ----------------
struct SubD { const float* bias; u16* out; float* ksum; int mode; };
struct Subs3 { SubD s[3]; };
__global__ __launch_bounds__(256) void gemm_qkv(const u16* __restrict__ A,
    const u16* __restrict__ W, Subs3 subs, int K, int wstride, int bstride, int ksstride){
  const int tid = threadIdx.x, lane = tid&63, w = tid>>6;
  const int quad = lane>>4, l15 = lane&15;
  const int2 swz = xcd_swz();
  const int bn = swz.x, bm = swz.y;
  const int iset = bm>>7;
  const int wm = w&1, wn = w>>1;
  fx4 acc[4][4];
  #pragma unroll
  for(int i=0;i<4;i++)
    #pragma unroll
    for(int j=0;j<4;j++) acc[i][j] = (fx4){0.f,0.f,0.f,0.f};
  const u16* Ab = A + (size_t)bm*128*K;
  const u16* Wb = W + (size_t)iset*wstride + (size_t)bn*128*K;
  KLOOP128_RR(Ab, Wb, K)
  const SubD sub = subs.s[bn>>2];
  const int colw = (bn&3)*128 + wn*64;
  const float* bias = sub.bias + iset*bstride;
  float bcol[4];
  #pragma unroll
  for(int nt=0;nt<4;nt++) bcol[nt] = bias[colw + nt*16 + l15];

  if(sub.mode==1){
    float ksacc[4] = {0.f,0.f,0.f,0.f};
    #pragma unroll
    for(int mt=0;mt<4;mt++)
      #pragma unroll
      for(int r=0;r<4;r++){
        float v0=acc[mt][0][r]+bcol[0], v1=acc[mt][1][r]+bcol[1];
        float v2=acc[mt][2][r]+bcol[2], v3=acc[mt][3][r]+bcol[3];
        float mx = fmaxf(fmaxf(v0,v1),fmaxf(v2,v3));
        mx = fmaxf(mx,__shfl_xor(mx,1,64)); mx = fmaxf(mx,__shfl_xor(mx,2,64));
        mx = fmaxf(mx,__shfl_xor(mx,4,64)); mx = fmaxf(mx,__shfl_xor(mx,8,64));
        float e0=__expf(v0-mx), e1=__expf(v1-mx), e2=__expf(v2-mx), e3=__expf(v3-mx);
        float s = e0+e1+e2+e3;
        s += __shfl_xor(s,1,64); s += __shfl_xor(s,2,64);
        s += __shfl_xor(s,4,64); s += __shfl_xor(s,8,64);
        float inv = __fdividef(1.f, s);
        e0*=inv; e1*=inv; e2*=inv; e3*=inv;
        ksacc[0]+=e0; ksacc[1]+=e1; ksacc[2]+=e2; ksacc[3]+=e3;
        int row = bm*128 + wm*64 + mt*16 + quad*4 + r;
        size_t rb = (size_t)row*512;
        sub.out[rb+colw+ 0+l15]=f2bf(e0); sub.out[rb+colw+16+l15]=f2bf(e1);
        sub.out[rb+colw+32+l15]=f2bf(e2); sub.out[rb+colw+48+l15]=f2bf(e3);
      }
    if(sub.ksum){
      int b = (bm&127)>>5;
      float* ks = sub.ksum + iset*ksstride + b*512;
      #pragma unroll
      for(int nt=0;nt<4;nt++){
        float s = ksacc[nt];
        s += __shfl_xor(s,16,64); s += __shfl_xor(s,32,64);
        if(quad==0) atomicAdd(&ks[colw + nt*16 + l15], s);
      }
    }
  } else {
    #pragma unroll
    for(int mt=0;mt<4;mt++)
      #pragma unroll
      for(int r=0;r<4;r++){
        int row = bm*128 + wm*64 + mt*16 + quad*4 + r;
        size_t rb = (size_t)row*512;
        #pragma unroll
        for(int nt=0;nt<4;nt++)
          sub.out[rb + colw + nt*16 + l15] = f2bf(acc[mt][nt][r] + bcol[nt]);
      }
  }
}

// ---------------- CA q-proj (BN=64, no-LDS): softmax epilogue, grid (8,128) ----------------
__global__ __launch_bounds__(256) void gemm_q64(const u16* __restrict__ A,
    const u16* __restrict__ W, const float* __restrict__ bias, u16* __restrict__ out){
  const int tid = threadIdx.x, lane = tid&63, w = tid>>6;
  const int quad = lane>>4, l15 = lane&15;
  const int2 swz = xcd_swz();
  const int bn = swz.x, bm = swz.y;
  fx4 acc[2][4];
  #pragma unroll
  for(int i=0;i<2;i++)
    #pragma unroll
    for(int j=0;j<4;j++) acc[i][j] = (fx4){0.f,0.f,0.f,0.f};
  const u16* Ab = A + (size_t)bm*128*512;
  const u16* Wb = W + (size_t)bn*64*512;
  KLOOP64_RR(Ab, Wb, 512)
  const int colb = bn*64;
  float bcol[4];
  #pragma unroll
  for(int nt=0;nt<4;nt++) bcol[nt] = bias[colb + nt*16 + l15];
  #pragma unroll
  for(int mt=0;mt<2;mt++)
    #pragma unroll
    for(int r=0;r<4;r++){
      float v0=acc[mt][0][r]+bcol[0], v1=acc[mt][1][r]+bcol[1];
      float v2=acc[mt][2][r]+bcol[2], v3=acc[mt][3][r]+bcol[3];
      float mx = fmaxf(fmaxf(v0,v1),fmaxf(v2,v3));
      mx = fmaxf(mx,__shfl_xor(mx,1,64)); mx = fmaxf(mx,__shfl_xor(mx,2,64));
      mx = fmaxf(mx,__shfl_xor(mx,4,64)); mx = fmaxf(mx,__shfl_xor(mx,8,64));
      float e0=__expf(v0-mx), e1=__expf(v1-mx), e2=__expf(v2-mx), e3=__expf(v3-mx);
      float s = e0+e1+e2+e3;
      s += __shfl_xor(s,1,64); s += __shfl_xor(s,2,64);
      s += __shfl_xor(s,4,64); s += __shfl_xor(s,8,64);
      float inv = __fdividef(1.f, s);
      e0*=inv; e1*=inv; e2*=inv; e3*=inv;
      int row = bm*128 + w*32 + mt*16 + quad*4 + r;
      size_t rb = (size_t)row*512;
      out[rb+colb+ 0+l15]=f2bf(e0); out[rb+colb+16+l15]=f2bf(e1);
      out[rb+colb+32+l15]=f2bf(e2); out[rb+colb+48+l15]=f2bf(e3);
    }
}

// -------- out/down-proj (BN=64, no-LDS): C = A*W^T + bias + res -> fp32 row-major --------
__global__ __launch_bounds__(256) void gemm_dn64(const u16* __restrict__ A,
    const u16* __restrict__ W, const float* __restrict__ bias,
    const float* __restrict__ res, float* __restrict__ out, int N, int K){
  const int tid = threadIdx.x, lane = tid&63, w = tid>>6;
  const int quad = lane>>4, l15 = lane&15;
  const int2 swz = xcd_swz();
  const int bn = swz.x, bm = swz.y;
  fx4 acc[2][4];
  #pragma unroll
  for(int i=0;i<2;i++)
    #pragma unroll
    for(int j=0;j<4;j++) acc[i][j] = (fx4){0.f,0.f,0.f,0.f};
  const u16* Ab = A + (size_t)bm*128*K;
  const u16* Wb = W + (size_t)bn*64*K;
  KLOOP64_RR(Ab, Wb, K)
  const int colb = bn*64;
  float bcol[4];
  #pragma unroll
  for(int nt=0;nt<4;nt++) bcol[nt] = bias[colb + nt*16 + l15];
  #pragma unroll
  for(int mt=0;mt<2;mt++)
    #pragma unroll
    for(int r=0;r<4;r++){
      int row = bm*128 + w*32 + mt*16 + quad*4 + r;
      size_t rb = (size_t)row*N;
      #pragma unroll
      for(int nt=0;nt<4;nt++){
        int col = colb + nt*16 + l15;
        out[rb+col] = res[rb+col] + acc[mt][nt][r] + bcol[nt];
      }
    }
}

// ------- FFN up-proj (no-LDS): C = A*W^T + bias -> gelu -> bf16 FRAGMENT layout -------
__global__ __launch_bounds__(256) void gemm_up(const u16* __restrict__ A,
    const u16* __restrict__ W, const float* __restrict__ bias,
    u16* __restrict__ out, int N, int K){
  const int tid = threadIdx.x, lane = tid&63, w = tid>>6;
  const int quad = lane>>4, l15 = lane&15;
  const int2 swz = xcd_swz();
  const int bn = swz.x, bm = swz.y;
  const int wm = w&1, wn = w>>1;
  fx4 acc[4][4];
  #pragma unroll
  for(int i=0;i<4;i++)
    #pragma unroll
    for(int j=0;j<4;j++) acc[i][j] = (fx4){0.f,0.f,0.f,0.f};
  const u16* Ab = A + (size_t)bm*128*K;
  const u16* Wb = W + (size_t)bn*128*K;
  KLOOP128_RR(Ab, Wb, K)
  const int colbase = bn*128 + wn*64;
  float bcol[4];
  #pragma unroll
  for(int nt=0;nt<4;nt++) bcol[nt] = bias[colbase + nt*16 + l15];
  #pragma unroll
  for(int mt=0;mt<4;mt++)
    #pragma unroll
    for(int r=0;r<4;r++){
      int row = bm*128 + wm*64 + mt*16 + quad*4 + r;
      #pragma unroll
      for(int nt=0;nt<4;nt++){
        int col = colbase + nt*16 + l15;
        out[faddr(row, col, N)] = f2bf(gelu_fast(acc[mt][nt][r] + bcol[nt]));
      }
    }
}

// ---------------- ctx[i,b,h][d1][d2] = sum_t k[t][d1] v[t][d2] (MFMA over t) ----------------
__global__ __launch_bounds__(256) void ctx_kernel(const u16* __restrict__ kb,
    const u16* __restrict__ vb, float* __restrict__ ctx, size_t kstride){
  __shared__ __align__(16) u16 lk[64*72];  // transposed [d][t], stride 72
  __shared__ __align__(16) u16 lv[64*72];
  const int tid=threadIdx.x, lane=tid&63, w=tid>>6, quad=lane>>4, l15=lane&15;
  const int bh2 = blockIdx.x, i = bh2>>5, h = bh2&7, b = (bh2>>3)&3;
  const u16* kbase = kb + (size_t)i*kstride;
  const u16* vbase = vb + (size_t)i*kstride;
  const size_t rowbase = (size_t)b*4096 + (size_t)blockIdx.y*512;
  const int mt0=(w&1)*32, nt0=(w>>1)*32;
  fx4 acc[2][2];
  #pragma unroll
  for(int x=0;x<2;x++)
    #pragma unroll
    for(int j=0;j<2;j++) acc[x][j] = (fx4){0.f,0.f,0.f,0.f};
  const int tl = tid>>2, part = tid&3;
  for(int it=0; it<8; it++){
    __syncthreads();
    {
      size_t gro = (rowbase + it*64 + tl)*512 + h*64 + part*16;
      bh8 k0 = *(const bh8*)(kbase + gro); bh8 k1 = *(const bh8*)(kbase + gro + 8);
      bh8 v0 = *(const bh8*)(vbase + gro); bh8 v1 = *(const bh8*)(vbase + gro + 8);
      #pragma unroll
      for(int j=0;j<8;j++){
        lk[(part*16+j  )*72 + tl] = (u16)k0[j];
        lk[(part*16+8+j)*72 + tl] = (u16)k1[j];
        lv[(part*16+j  )*72 + tl] = (u16)v0[j];
        lv[(part*16+8+j)*72 + tl] = (u16)v1[j];
      }
    }
    __syncthreads();
    #pragma unroll
    for(int ks=0;ks<2;ks++){
      bh8 a0 = *(const bh8*)&lk[(mt0    +l15)*72 + ks*32 + quad*8];
      bh8 a1 = *(const bh8*)&lk[(mt0+16 +l15)*72 + ks*32 + quad*8];
      bh8 b0 = *(const bh8*)&lv[(nt0    +l15)*72 + ks*32 + quad*8];
      bh8 b1 = *(const bh8*)&lv[(nt0+16 +l15)*72 + ks*32 + quad*8];
      acc[0][0] = __builtin_amdgcn_mfma_f32_16x16x32_bf16(a0,b0,acc[0][0],0,0,0);
      acc[0][1] = __builtin_amdgcn_mfma_f32_16x16x32_bf16(a0,b1,acc[0][1],0,0,0);
      acc[1][0] = __builtin_amdgcn_mfma_f32_16x16x32_bf16(a1,b0,acc[1][0],0,0,0);
      acc[1][1] = __builtin_amdgcn_mfma_f32_16x16x32_bf16(a1,b1,acc[1][1],0,0,0);
    }
  }
  float* cb = ctx + (size_t)bh2*4096;
  #pragma unroll
  for(int mi=0;mi<2;mi++)
    #pragma unroll
    for(int ni=0;ni<2;ni++)
      #pragma unroll
      for(int r=0;r<4;r++){
        int d1 = mt0 + mi*16 + quad*4 + r;
        int d2 = nt0 + ni*16 + l15;
        atomicAdd(&cb[d1*64 + d2], acc[mi][ni][r]);
      }
}

// --- out = q + sum_i (q @ ctx_i)*Dinv_i; writes OUTB in FRAGMENT layout (K=512) ---
template<int NIN>
__global__ __launch_bounds__(256) void apply_kernel(const u16* __restrict__ q,
    const float* __restrict__ ctx, const float* __restrict__ ksum, float eps,
    u16* __restrict__ out){
  __shared__ __align__(16) u16 lctx[(NIN+1)*64*72];
  const int tid=threadIdx.x, lane=tid&63, w=tid>>6, quad=lane>>4, l15=lane&15;
  const int bh = blockIdx.x, b=bh>>3, h=bh&7;
  {
    int base = tid*16;
    int d1 = base>>6, d2b = base&63;
    #pragma unroll
    for(int s=0;s<=NIN;s++){
      u16* dst = &lctx[s*64*72];
      if(s<NIN){
        const float* sp = ctx + ((size_t)s*32 + bh)*4096 + base;
        #pragma unroll
        for(int j=0;j<16;j++) dst[(d2b+j)*72 + d1] = f2bf(sp[j]);
      } else {
        #pragma unroll
        for(int j=0;j<16;j++) dst[(d2b+j)*72 + d1] = ((d2b+j)==d1) ? (u16)0x3f80 : (u16)0;
      }
    }
  }
  float kslo[NIN][8], kshi[NIN][8];
  #pragma unroll
  for(int s=0;s<NIN;s++){
    const float* ks = ksum + s*2048 + b*512 + h*64;
    #pragma unroll
    for(int j=0;j<8;j++){ kslo[s][j] = ks[quad*8+j]; kshi[s][j] = ks[32+quad*8+j]; }
  }
  __syncthreads();
  bh8 bfr[NIN+1][4][2];
  #pragma unroll
  for(int s=0;s<=NIN;s++)
    #pragma unroll
    for(int nt=0;nt<4;nt++)
      #pragma unroll
      for(int ks=0;ks<2;ks++)
        bfr[s][nt][ks] = *(const bh8*)&lctx[s*64*72 + (nt*16+l15)*72 + ks*32 + quad*8];
  const size_t tb0 = (size_t)b*4096 + (size_t)blockIdx.y*256 + w*64;
  for(int g=0;g<4;g++){
    size_t tb = tb0 + g*16;
    const u16* qr = q + (tb + l15)*512 + h*64;
    bh8 a0 = *(const bh8*)(qr + quad*8);
    bh8 a1 = *(const bh8*)(qr + 32 + quad*8);
    float dv[NIN][4];
    #pragma unroll
    for(int s=0;s<NIN;s++){
      float part = 0.f;
      #pragma unroll
      for(int j=0;j<8;j++)
        part += bf2f((u16)a0[j])*kslo[s][j] + bf2f((u16)a1[j])*kshi[s][j];
      part += __shfl_xor(part,16,64); part += __shfl_xor(part,32,64);
      #pragma unroll
      for(int r=0;r<4;r++)
        dv[s][r] = __fdividef(1.f, __shfl(part, quad*4+r, 64) + eps);
    }
    fx4 outv[4];
    #pragma unroll
    for(int nt=0;nt<4;nt++) outv[nt] = (fx4){0.f,0.f,0.f,0.f};
    #pragma unroll
    for(int s=0;s<=NIN;s++){
      fx4 c[4];
      #pragma unroll
      for(int nt=0;nt<4;nt++){
        c[nt] = (fx4){0.f,0.f,0.f,0.f};
        c[nt] = __builtin_amdgcn_mfma_f32_16x16x32_bf16(a0, bfr[s][nt][0], c[nt], 0,0,0);
        c[nt] = __builtin_amdgcn_mfma_f32_16x16x32_bf16(a1, bfr[s][nt][1], c[nt], 0,0,0);
      }
      #pragma unroll
      for(int nt=0;nt<4;nt++)
        #pragma unroll
        for(int r=0;r<4;r++) outv[nt][r] += c[nt][r]*((s==NIN)?1.f:dv[s][r]);
    }
    #pragma unroll
    for(int nt=0;nt<4;nt++)
      #pragma unroll
      for(int r=0;r<4;r++)
        out[faddr((int)tb + quad*4 + r, h*64 + nt*16 + l15, 512)] = f2bf(outv[nt][r]);
  }
}

// =========================================================================
extern "C" void kernel_launch(void* const* d_in, const int* in_sizes, int n_in,
                              void* d_out, int out_size, void* d_ws, size_t ws_size,
                              hipStream_t stream){
  const float* x_in =(const float*)d_in[0];
  const float* ys   =(const float*)d_in[1];
  const float* ln1g =(const float*)d_in[2],  *ln1b=(const float*)d_in[3];
  const float* ln2g =(const float*)d_in[4],  *ln2b=(const float*)d_in[5];
  const float* ln3g =(const float*)d_in[6],  *ln3b=(const float*)d_in[7];
  const float* ln4g =(const float*)d_in[8],  *ln4b=(const float*)d_in[9];
  const float* ln5g =(const float*)d_in[10], *ln5b=(const float*)d_in[11];
  const float* ca_wq=(const float*)d_in[12], *ca_bq=(const float*)d_in[13];
  const float* ca_wk=(const float*)d_in[14], *ca_bk=(const float*)d_in[15];
  const float* ca_wv=(const float*)d_in[16], *ca_bv=(const float*)d_in[17];
  const float* ca_wo=(const float*)d_in[18], *ca_bo=(const float*)d_in[19];
  const float* sa_wq=(const float*)d_in[20], *sa_bq=(const float*)d_in[21];
  const float* sa_wk=(const float*)d_in[22], *sa_bk=(const float*)d_in[23];
  const float* sa_wv=(const float*)d_in[24], *sa_bv=(const float*)d_in[25];
  const float* sa_wo=(const float*)d_in[26], *sa_bo=(const float*)d_in[27];
  const float* f1w1 =(const float*)d_in[28], *f1b1=(const float*)d_in[29];
  const float* f1w2 =(const float*)d_in[30], *f1b2=(const float*)d_in[31];
  const float* f2w1 =(const float*)d_in[32], *f2b1=(const float*)d_in[33];
  const float* f2w2 =(const float*)d_in[34], *f2b2=(const float*)d_in[35];

  char* p = (char*)d_ws;
  u16*   WBF = (u16*)p;    p += 13631488;   // bf16 weights (FRAGMENT layout per matrix)
  float* XW  = (float*)p;  p += 33554432;   // residual stream fp32 [16384,512]
  u16*   XN2 = (u16*)p;    p += 33554432;   // LN out (frag layout), up to 2x16384 rows
  u16*   QB  = (u16*)p;    p += 16777216;   // q softmax out (row-major)
  u16*   R1  = (u16*)p;    p += 67108864;   // FFN hidden (frag) OR stacked KB2|VB2 (row)
  u16*   OUTB= (u16*)p;    p += 16777216;   // attn out / x-LN staging (frag layout)
  float* SM  = (float*)p;  p += 1597440;    // ctx + ksum (zeroed)
  u16*   XN  = XN2;
  u16*   KB2 = R1;
  u16*   VB2 = R1 + 16777216;
  u16*   HB  = R1;
  float* CTXC = SM;                          // [2][32][4096]
  float* CTXS = SM + 262144;                 // [32][4096]
  float* KSC  = SM + 393216;                 // [2][4][512]
  float* KSS  = SM + 397312;                 // [4][512]

  WDesc wd;
  const float* wsrc[14] = {ca_wq, ca_wk, ca_wv, ca_wk+262144, ca_wv+262144, ca_wo,
                           sa_wq, sa_wk, sa_wv, sa_wo, f1w1, f1w2, f2w1, f2w2};
  const int    woff[14] = {0, 262144, 524288, 786432, 1048576, 1310720,
                           1572864, 1835008, 2097152, 2359296,
                           2621440, 3670016, 4718592, 5767168};
  const int    wksh[14] = {9,9,9,9,9,9, 9,9,9,9, 9,11, 9,11};
  for(int i=0;i<14;i++){ wd.src[i]=wsrc[i]; wd.off[i]=woff[i]; wd.ksh[i]=wksh[i]; }
  convw_kernel<<<26624,256,0,stream>>>(wd, WBF);
  hipMemsetAsync(SM, 0, 399360*sizeof(float), stream);

  SubD zsub = {nullptr,nullptr,nullptr,0};

  // ---- cross attention ----
  ln_kernel<<<4096,256,0,stream>>>(x_in, ln1g, ln1b, OUTB);   // x-LN staged (frag) in OUTB
  lny_kernel<<<8192,256,0,stream>>>(ys, ln2g, ln2b, XN2);     // both ys LNs (frag)
  gemm_q64<<<dim3(8,128),256,0,stream>>>(OUTB, WBF+0, ca_bq, QB);
  { Subs3 s = {{ {ca_bk, KB2, KSC, 1}, {ca_bv, VB2, nullptr, 0}, zsub }};
    gemm_qkv<<<dim3(8,256),256,0,stream>>>(XN2, WBF+262144, s, 512,
                                           524288, 512, 2048); }  // i = bm>>7
  ctx_kernel<<<dim3(64,8),256,0,stream>>>(KB2, VB2, CTXC, (size_t)16384*512);
  apply_kernel<2><<<dim3(32,16),256,0,stream>>>(QB, CTXC, KSC, 1e-8f, OUTB);
  gemm_dn64<<<dim3(8,128),256,0,stream>>>(OUTB, WBF+1310720, ca_bo, x_in, XW, 512, 512);

  // ---- FFN 1 ----
  ln_kernel<<<4096,256,0,stream>>>(XW, ln3g, ln3b, XN);
  gemm_up<<<dim3(16,128),256,0,stream>>>(XN, WBF+2621440, f1b1, HB, 2048, 512);
  gemm_dn64<<<dim3(8,128),256,0,stream>>>(HB, WBF+3670016, f1b2, XW, XW, 512, 2048);

  // ---- linear self attention ----
  ln_kernel<<<4096,256,0,stream>>>(XW, ln4g, ln4b, XN);
  { Subs3 s = {{ {sa_bq, QB, nullptr, 1}, {sa_bk, KB2, KSS, 1}, {sa_bv, VB2, nullptr, 0} }};
    gemm_qkv<<<dim3(12,128),256,0,stream>>>(XN, WBF+1572864, s, 512, 0,0,0); }
  ctx_kernel<<<dim3(32,8),256,0,stream>>>(KB2, VB2, CTXS, 0);
  apply_kernel<1><<<dim3(32,16),256,0,stream>>>(QB, CTXS, KSS, 0.f, OUTB);
  gemm_dn64<<<dim3(8,128),256,0,stream>>>(OUTB, WBF+2359296, sa_bo, XW, XW, 512, 512);

  // ---- FFN 2 ----
  ln_kernel<<<4096,256,0,stream>>>(XW, ln5g, ln5b, XN);
  gemm_up<<<dim3(16,128),256,0,stream>>>(XN, WBF+4718592, f2b1, HB, 2048, 512);
  gemm_dn64<<<dim3(8,128),256,0,stream>>>(HB, WBF+5767168, f2b2, XW, (float*)d_out, 512, 2048);
}

// Round 9
// 745.118 us; speedup vs baseline: 1.0046x; 1.0046x over previous
//
// CrossAttentionBlock_56813827392085 — fused transformer block, bf16 MFMA internals. R15:
//  = R14 (R12 base + A-prefetch depth 2 + hoisted incremental addressing) with the R14
//  RACE FIXED: every vmem issue group (global_load_lds stage / plain A-frag loads) is
//  followed by asm volatile(""::: "memory") so issue order == program order. R14 dropped
//  these and the compiler hoisted prologue A-loads above the B-stage, shifting the vmem
//  queue so vmcnt(6) no longer covered the lsB[0] stage -> stale LDS reads (absmax 0.33).
//  Pinned-queue derivation (128^2): prologue {B0:2,A0:4,A1:4}; steady first-half queue
//  {A(j):4,B(j):2,A(j+1):4,B(j+1):2} -> vmcnt(6) completes exactly A(j),B(j); tail
//  vmcnt(0). BN=64: {A(j):2,B(j):1,A(j+1):2,B(j+1):1} -> vmcnt(3). SYNC up-proj loop
//  unchanged (syncthreads is a real fence, was never at risk).
#include <hip/hip_runtime.h>
#include <hip/hip_bf16.h>
#include <math.h>
#include <stdint.h>

typedef unsigned short u16;
typedef __attribute__((ext_vector_type(8))) short bh8;
typedef __attribute__((ext_vector_type(4))) float fx4;

#define DEV static __device__ __forceinline__
#define PIN asm volatile("" ::: "memory");

DEV float bf2f(u16 u){ union{unsigned u; float f;} v; v.u = ((unsigned)u)<<16; return v.f; }
DEV u16 f2bf(float f){ union{float f; unsigned u;} v; v.f = f;
  return (u16)((v.u + 0x7fffu + ((v.u>>16)&1u))>>16); }               // RNE

DEV void async16(const u16* g, u16* l){
  __builtin_amdgcn_global_load_lds((__attribute__((address_space(1))) void*)(uintptr_t)g,
                                   (__attribute__((address_space(3))) void*)l, 16, 0, 0);
}

// MFMA-A fragment address for a [rows][Kbuf] bf16 buffer.
DEV size_t faddr(int row, int col, int Kbuf){
  return (size_t)(row>>4)*((size_t)Kbuf*16)
       + (size_t)((col>>3)*128 + (row&15)*8 + (col&7));
}

// gelu tanh-approx via sigmoid identity: x * 1/(1+exp(x*(-1.59577 - 0.0713548*x^2)))
DEV float gelu_fast(float x){
  float x2 = x*x;
  float t  = __builtin_fmaf(x2, -0.071354816f, -1.5957691216f);
  float e  = __expf(x*t);
  return __fdividef(x, 1.f + e);
}

// XCD-aware bijective block swizzle (requires nwg%8==0 — all GEMM grids here satisfy).
DEV int2 xcd_swz(){
  const int gx  = gridDim.x;
  const int ord = blockIdx.y*gx + blockIdx.x;
  const int nwg = gx*gridDim.y;
  const int wg  = (ord&7)*(nwg>>3) + (ord>>3);
  int2 r; r.x = wg % gx; r.y = wg / gx; return r;
}

// ---------------- weight fp32 -> bf16 pack (row-major) ----------------
struct WDesc { const float* src[14]; int off[14]; };
__global__ __launch_bounds__(256) void convw_kernel(WDesc d, u16* __restrict__ dst){
  int i = blockIdx.x*256 + threadIdx.x;
  int s = 0;
  #pragma unroll
  for(int j=1;j<14;j++) if(i >= d.off[j]) s = j;
  dst[i] = f2bf(d.src[s][i - d.off[s]]);
}

// ---------------- LayerNorm (C=512), fp32 in -> bf16 FRAGMENT-layout out ----------------
DEV float wsum64(float s){
  s += __shfl_xor(s,1,64);  s += __shfl_xor(s,2,64);  s += __shfl_xor(s,4,64);
  s += __shfl_xor(s,8,64);  s += __shfl_xor(s,16,64); s += __shfl_xor(s,32,64);
  return s;
}
DEV void ln_row(const float* xrow, const float* g, const float* bta, u16* orow, int lane){
  const float4* xr = (const float4*)xrow + lane*2;
  float4 a = xr[0], c = xr[1];
  float s = a.x+a.y+a.z+a.w + c.x+c.y+c.z+c.w;
  float mean = wsum64(s) * (1.f/512.f);
  float d0=a.x-mean,d1=a.y-mean,d2=a.z-mean,d3=a.w-mean;
  float d4=c.x-mean,d5=c.y-mean,d6=c.z-mean,d7=c.w-mean;
  float sv = d0*d0+d1*d1+d2*d2+d3*d3+d4*d4+d5*d5+d6*d6+d7*d7;
  float rstd = rsqrtf(wsum64(sv)*(1.f/512.f) + 1e-5f);
  const float4* gr = (const float4*)g   + lane*2;
  const float4* br = (const float4*)bta + lane*2;
  float4 g0=gr[0], g1=gr[1], b0=br[0], b1=br[1];
  bh8 o;
  o[0]=(short)f2bf(d0*rstd*g0.x+b0.x); o[1]=(short)f2bf(d1*rstd*g0.y+b0.y);
  o[2]=(short)f2bf(d2*rstd*g0.z+b0.z); o[3]=(short)f2bf(d3*rstd*g0.w+b0.w);
  o[4]=(short)f2bf(d4*rstd*g1.x+b1.x); o[5]=(short)f2bf(d5*rstd*g1.y+b1.y);
  o[6]=(short)f2bf(d6*rstd*g1.z+b1.z); o[7]=(short)f2bf(d7*rstd*g1.w+b1.w);
  *(bh8*)(orow + (size_t)lane*128) = o;
}
__global__ __launch_bounds__(256) void ln_kernel(const float* __restrict__ x,
    const float* __restrict__ g, const float* __restrict__ bta, u16* __restrict__ out){
  int row  = blockIdx.x*4 + (threadIdx.x>>6);
  u16* orow = out + (size_t)(row>>4)*8192 + (size_t)(row&15)*8;
  ln_row(x + (size_t)row*512, g, bta, orow, threadIdx.x&63);
}
__global__ __launch_bounds__(256) void lny_kernel(const float* __restrict__ ys,
    const float* __restrict__ g2, const float* __restrict__ b2, u16* __restrict__ out){
  int row  = blockIdx.x*4 + (threadIdx.x>>6);
  int i = row>>14;
  u16* orow = out + (size_t)(row>>4)*8192 + (size_t)(row&15)*8;
  ln_row(ys + (size_t)row*512, g2 + i*512, b2 + i*512, orow, threadIdx.x&63);
}

// ==== GEMM K-loops: B in 2-ring LDS (swizzled, conflict-free), A reg-prefetch depth 2 ====
// C/D layout: out_row = quad*4+r (within 16), out_col = l15.
#define PREF4s(F, step)                                                              \
    _Pragma("unroll")                                                                \
    for(int t=0;t<4;t++)                                                             \
      F[t] = *(const bh8*)(Ap + (size_t)t*AS + (size_t)(step)*512);
#define PREF2s(F, step)                                                              \
    _Pragma("unroll")                                                                \
    for(int t=0;t<2;t++)                                                             \
      F[t] = *(const bh8*)(Ap + (size_t)t*AS + (size_t)(step)*512);

#define MFMA128(AF, CUR)                                                             \
    { bh8 bfx[4];                                                                    \
      _Pragma("unroll")                                                              \
      for(int t=0;t<4;t++)                                                           \
        bfx[t] = *(const bh8*)&lsB[CUR][(wn*64+t*16+l15)*32 + rsw*8];                \
      _Pragma("unroll")                                                              \
      for(int mt=0;mt<4;mt++)                                                        \
        _Pragma("unroll")                                                            \
        for(int nt=0;nt<4;nt++)                                                      \
          acc[mt][nt] = __builtin_amdgcn_mfma_f32_16x16x32_bf16(AF[mt], bfx[nt], acc[mt][nt], 0,0,0); }

#define MFMA64(AF, CUR)                                                              \
    { bh8 bfx[4];                                                                    \
      _Pragma("unroll")                                                              \
      for(int t=0;t<4;t++)                                                           \
        bfx[t] = *(const bh8*)&lsB[CUR][(t*16+l15)*32 + rsw*8];                      \
      _Pragma("unroll")                                                              \
      for(int mt=0;mt<2;mt++)                                                        \
        _Pragma("unroll")                                                            \
        for(int nt=0;nt<4;nt++)                                                      \
          acc[mt][nt] = __builtin_amdgcn_mfma_f32_16x16x32_bf16(AF[mt], bfx[nt], acc[mt][nt], 0,0,0); }

// 128x128 block, 2x2 waves: counted loop, A depth-2, hoisted pointers, PINNED order.
#define KLOOP_CNT128(Ab, Wb, K, WTILE)                                               \
  const int srow = w*32 + (lane>>2);                                                 \
  const int scol = (((lane&3) ^ ((srow>>1)&3)) * 8);                                 \
  const int rsw  = ((l15>>1)&3) ^ quad;                                              \
  const u16* Bg0 = (Wb) + (size_t)srow*(K) + scol;                                   \
  const u16* Bg1 = (Wb) + (size_t)(srow+16)*(K) + scol;                              \
  const u16* Ap  = (Ab) + (size_t)(WTILE)*16*(K) + lane*8;                           \
  const size_t AS = (size_t)16*(K);                                                  \
  bh8 afA[4], afB[4];                                                                \
  async16(Bg0, &lsB[0][(w*32)*32]); async16(Bg1, &lsB[0][(w*32+16)*32]);             \
  PIN                                                                                \
  PREF4s(afA, 0)                                                                     \
  PIN                                                                                \
  PREF4s(afB, 1)                                                                     \
  PIN                                                                                \
  const int NS = (K)>>5;                                                             \
  for(int j=0;j<NS;j+=2){                                                            \
    if(j+1<NS){ async16(Bg0+(j+1)*32, &lsB[1][(w*32)*32]);                           \
                async16(Bg1+(j+1)*32, &lsB[1][(w*32+16)*32]);                        \
                PIN                                                                  \
                asm volatile("s_waitcnt vmcnt(6)" ::: "memory"); }                   \
    else      { asm volatile("s_waitcnt vmcnt(0)" ::: "memory"); }                   \
    __builtin_amdgcn_s_barrier();                                                    \
    MFMA128(afA, 0)                                                                  \
    if(j+2<NS){ PREF4s(afA, j+2) PIN }                                               \
    __builtin_amdgcn_s_barrier();                                                    \
    if(j+1<NS){                                                                      \
      if(j+2<NS){ async16(Bg0+(j+2)*32, &lsB[0][(w*32)*32]);                         \
                  async16(Bg1+(j+2)*32, &lsB[0][(w*32+16)*32]);                      \
                  PIN                                                                \
                  asm volatile("s_waitcnt vmcnt(6)" ::: "memory"); }                 \
      else      { asm volatile("s_waitcnt vmcnt(0)" ::: "memory"); }                 \
      __builtin_amdgcn_s_barrier();                                                  \
      MFMA128(afB, 1)                                                                \
      if(j+3<NS){ PREF4s(afB, j+3) PIN }                                             \
      __builtin_amdgcn_s_barrier();                                                  \
    }                                                                                \
  }

// SYNC variant for the gelu up-proj (syncthreads = real fence, R12-proven safe).
#define KLOOP_SYNC128(Ab, Wb, K, WTILE)                                              \
  const int srow = w*32 + (lane>>2);                                                 \
  const int scol = (((lane&3) ^ ((srow>>1)&3)) * 8);                                 \
  const int rsw  = ((l15>>1)&3) ^ quad;                                              \
  const u16* Bg0 = (Wb) + (size_t)srow*(K) + scol;                                   \
  const u16* Bg1 = (Wb) + (size_t)(srow+16)*(K) + scol;                              \
  const u16* Ap  = (Ab) + (size_t)(WTILE)*16*(K) + lane*8;                           \
  const size_t AS = (size_t)16*(K);                                                  \
  bh8 afA[4], afB[4];                                                                \
  async16(Bg0, &lsB[0][(w*32)*32]); async16(Bg1, &lsB[0][(w*32+16)*32]);             \
  PIN                                                                                \
  PREF4s(afA, 0)                                                                     \
  __syncthreads();                                                                   \
  const int NS = (K)>>5;                                                             \
  for(int j=0;j<NS;j+=2){                                                            \
    if(j+1<NS){ async16(Bg0+(j+1)*32, &lsB[1][(w*32)*32]);                           \
                async16(Bg1+(j+1)*32, &lsB[1][(w*32+16)*32]);                        \
                PIN                                                                  \
                PREF4s(afB, j+1) }                                                   \
    MFMA128(afA, 0)                                                                  \
    __syncthreads();                                                                 \
    if(j+1<NS){                                                                      \
      if(j+2<NS){ async16(Bg0+(j+2)*32, &lsB[0][(w*32)*32]);                         \
                  async16(Bg1+(j+2)*32, &lsB[0][(w*32+16)*32]);                      \
                  PIN                                                                \
                  PREF4s(afA, j+2) }                                                 \
      MFMA128(afB, 1)                                                                \
      __syncthreads();                                                               \
    }                                                                                \
  }

// 128x64 block, 4 waves stacked in M: counted loop, A depth-2, PINNED order.
#define KLOOP_CNT64(Ab, Wb, K)                                                       \
  const int browB = w*16 + (lane>>2);                                                \
  const int scolB = (((lane&3) ^ ((browB>>1)&3)) * 8);                               \
  const int rsw   = ((l15>>1)&3) ^ quad;                                             \
  const u16* Bg = (Wb) + (size_t)browB*(K) + scolB;                                  \
  const u16* Ap = (Ab) + (size_t)(w*2)*16*(K) + lane*8;                              \
  const size_t AS = (size_t)16*(K);                                                  \
  bh8 afA[2], afB[2];                                                                \
  async16(Bg, &lsB[0][(w*16)*32]);                                                   \
  PIN                                                                                \
  PREF2s(afA, 0)                                                                     \
  PIN                                                                                \
  PREF2s(afB, 1)                                                                     \
  PIN                                                                                \
  const int NS = (K)>>5;                                                             \
  for(int j=0;j<NS;j+=2){                                                            \
    if(j+1<NS){ async16(Bg+(j+1)*32, &lsB[1][(w*16)*32]);                            \
                PIN                                                                  \
                asm volatile("s_waitcnt vmcnt(3)" ::: "memory"); }                   \
    else      { asm volatile("s_waitcnt vmcnt(0)" ::: "memory"); }                   \
    __builtin_amdgcn_s_barrier();                                                    \
    MFMA64(afA, 0)                                                                   \
    if(j+2<NS){ PREF2s(afA, j+2) PIN }                                               \
    __builtin_amdgcn_s_barrier();                                                    \
    if(j+1<NS){                                                                      \
      if(j+2<NS){ async16(Bg+(j+2)*32, &lsB[0][(w*16)*32]);                          \
                  PIN                                                                \
                  asm volatile("s_waitcnt vmcnt(3)" ::: "memory"); }                 \
      else      { asm volatile("s_waitcnt vmcnt(0)" ::: "memory"); }                 \
      __builtin_amdgcn_s_barrier();                                                  \
      MFMA64(afB, 1)                                                                 \
      if(j+3<NS){ PREF2s(afB, j+3) PIN }                                             \
      __builtin_amdgcn_s_barrier();                                                  \
    }                                                                                \
  }

// ---------------- multi-output projection GEMM (BN=128, A frag-layout) ----------------
struct SubD { const float* bias; u16* out; float* ksum; int mode; };
struct Subs3 { SubD s[3]; };
__global__ __launch_bounds__(256) void gemm_qkv(const u16* __restrict__ A,
    const u16* __restrict__ W, Subs3 subs, int K, int wstride, int bstride, int ksstride){
  __shared__ __align__(16) u16 lsB[2][128*32];
  const int tid = threadIdx.x, lane = tid&63, w = tid>>6;
  const int quad = lane>>4, l15 = lane&15;
  const int2 swz = xcd_swz();
  const int bn = swz.x, bm = swz.y;
  const int iset = bm>>7;
  const int wm = w&1, wn = w>>1;
  fx4 acc[4][4];
  #pragma unroll
  for(int i=0;i<4;i++)
    #pragma unroll
    for(int j=0;j<4;j++) acc[i][j] = (fx4){0.f,0.f,0.f,0.f};
  const u16* Ab = A + (size_t)bm*128*K;
  const u16* Wb = W + (size_t)iset*wstride + (size_t)bn*128*K;
  KLOOP_CNT128(Ab, Wb, K, wm*4)
  const SubD sub = subs.s[bn>>2];
  const int colw = (bn&3)*128 + wn*64;
  const float* bias = sub.bias + iset*bstride;
  float bcol[4];
  #pragma unroll
  for(int nt=0;nt<4;nt++) bcol[nt] = bias[colw + nt*16 + l15];

  if(sub.mode==1){
    float ksacc[4] = {0.f,0.f,0.f,0.f};
    #pragma unroll
    for(int mt=0;mt<4;mt++)
      #pragma unroll
      for(int r=0;r<4;r++){
        float v0=acc[mt][0][r]+bcol[0], v1=acc[mt][1][r]+bcol[1];
        float v2=acc[mt][2][r]+bcol[2], v3=acc[mt][3][r]+bcol[3];
        float mx = fmaxf(fmaxf(v0,v1),fmaxf(v2,v3));
        mx = fmaxf(mx,__shfl_xor(mx,1,64)); mx = fmaxf(mx,__shfl_xor(mx,2,64));
        mx = fmaxf(mx,__shfl_xor(mx,4,64)); mx = fmaxf(mx,__shfl_xor(mx,8,64));
        float e0=__expf(v0-mx), e1=__expf(v1-mx), e2=__expf(v2-mx), e3=__expf(v3-mx);
        float s = e0+e1+e2+e3;
        s += __shfl_xor(s,1,64); s += __shfl_xor(s,2,64);
        s += __shfl_xor(s,4,64); s += __shfl_xor(s,8,64);
        float inv = __fdividef(1.f, s);
        e0*=inv; e1*=inv; e2*=inv; e3*=inv;
        ksacc[0]+=e0; ksacc[1]+=e1; ksacc[2]+=e2; ksacc[3]+=e3;
        int row = bm*128 + wm*64 + mt*16 + quad*4 + r;
        size_t rb = (size_t)row*512;
        sub.out[rb+colw+ 0+l15]=f2bf(e0); sub.out[rb+colw+16+l15]=f2bf(e1);
        sub.out[rb+colw+32+l15]=f2bf(e2); sub.out[rb+colw+48+l15]=f2bf(e3);
      }
    if(sub.ksum){
      int b = (bm&127)>>5;
      float* ks = sub.ksum + iset*ksstride + b*512;
      #pragma unroll
      for(int nt=0;nt<4;nt++){
        float s = ksacc[nt];
        s += __shfl_xor(s,16,64); s += __shfl_xor(s,32,64);
        if(quad==0) atomicAdd(&ks[colw + nt*16 + l15], s);
      }
    }
  } else {
    #pragma unroll
    for(int mt=0;mt<4;mt++)
      #pragma unroll
      for(int r=0;r<4;r++){
        int row = bm*128 + wm*64 + mt*16 + quad*4 + r;
        size_t rb = (size_t)row*512;
        #pragma unroll
        for(int nt=0;nt<4;nt++)
          sub.out[rb + colw + nt*16 + l15] = f2bf(acc[mt][nt][r] + bcol[nt]);
      }
  }
}

// ---------------- CA q-proj (BN=64): softmax epilogue, grid (8,128) ----------------
__global__ __launch_bounds__(256) void gemm_q64(const u16* __restrict__ A,
    const u16* __restrict__ W, const float* __restrict__ bias, u16* __restrict__ out){
  __shared__ __align__(16) u16 lsB[2][64*32];
  const int tid = threadIdx.x, lane = tid&63, w = tid>>6;
  const int quad = lane>>4, l15 = lane&15;
  const int2 swz = xcd_swz();
  const int bn = swz.x, bm = swz.y;
  fx4 acc[2][4];
  #pragma unroll
  for(int i=0;i<2;i++)
    #pragma unroll
    for(int j=0;j<4;j++) acc[i][j] = (fx4){0.f,0.f,0.f,0.f};
  const u16* Ab = A + (size_t)bm*128*512;
  const u16* Wb = W + (size_t)bn*64*512;
  KLOOP_CNT64(Ab, Wb, 512)
  const int colb = bn*64;
  float bcol[4];
  #pragma unroll
  for(int nt=0;nt<4;nt++) bcol[nt] = bias[colb + nt*16 + l15];
  #pragma unroll
  for(int mt=0;mt<2;mt++)
    #pragma unroll
    for(int r=0;r<4;r++){
      float v0=acc[mt][0][r]+bcol[0], v1=acc[mt][1][r]+bcol[1];
      float v2=acc[mt][2][r]+bcol[2], v3=acc[mt][3][r]+bcol[3];
      float mx = fmaxf(fmaxf(v0,v1),fmaxf(v2,v3));
      mx = fmaxf(mx,__shfl_xor(mx,1,64)); mx = fmaxf(mx,__shfl_xor(mx,2,64));
      mx = fmaxf(mx,__shfl_xor(mx,4,64)); mx = fmaxf(mx,__shfl_xor(mx,8,64));
      float e0=__expf(v0-mx), e1=__expf(v1-mx), e2=__expf(v2-mx), e3=__expf(v3-mx);
      float s = e0+e1+e2+e3;
      s += __shfl_xor(s,1,64); s += __shfl_xor(s,2,64);
      s += __shfl_xor(s,4,64); s += __shfl_xor(s,8,64);
      float inv = __fdividef(1.f, s);
      e0*=inv; e1*=inv; e2*=inv; e3*=inv;
      int row = bm*128 + w*32 + mt*16 + quad*4 + r;
      size_t rb = (size_t)row*512;
      out[rb+colb+ 0+l15]=f2bf(e0); out[rb+colb+16+l15]=f2bf(e1);
      out[rb+colb+32+l15]=f2bf(e2); out[rb+colb+48+l15]=f2bf(e3);
    }
}

// -------- out/down-proj (BN=64): C = A*W^T + bias + res -> fp32 row-major --------
__global__ __launch_bounds__(256) void gemm_dn64(const u16* __restrict__ A,
    const u16* __restrict__ W, const float* __restrict__ bias,
    const float* __restrict__ res, float* __restrict__ out, int N, int K){
  __shared__ __align__(16) u16 lsB[2][64*32];
  const int tid = threadIdx.x, lane = tid&63, w = tid>>6;
  const int quad = lane>>4, l15 = lane&15;
  const int2 swz = xcd_swz();
  const int bn = swz.x, bm = swz.y;
  fx4 acc[2][4];
  #pragma unroll
  for(int i=0;i<2;i++)
    #pragma unroll
    for(int j=0;j<4;j++) acc[i][j] = (fx4){0.f,0.f,0.f,0.f};
  const u16* Ab = A + (size_t)bm*128*K;
  const u16* Wb = W + (size_t)bn*64*K;
  KLOOP_CNT64(Ab, Wb, K)
  const int colb = bn*64;
  float bcol[4];
  #pragma unroll
  for(int nt=0;nt<4;nt++) bcol[nt] = bias[colb + nt*16 + l15];
  #pragma unroll
  for(int mt=0;mt<2;mt++)
    #pragma unroll
    for(int r=0;r<4;r++){
      int row = bm*128 + w*32 + mt*16 + quad*4 + r;
      size_t rb = (size_t)row*N;
      #pragma unroll
      for(int nt=0;nt<4;nt++){
        int col = colb + nt*16 + l15;
        out[rb+col] = res[rb+col] + acc[mt][nt][r] + bcol[nt];
      }
    }
}

// ------- FFN up-proj: C = A*W^T + bias -> gelu -> bf16 FRAGMENT layout (SYNC loop) -------
__global__ __launch_bounds__(256) void gemm_up(const u16* __restrict__ A,
    const u16* __restrict__ W, const float* __restrict__ bias,
    u16* __restrict__ out, int N, int K){
  __shared__ __align__(16) u16 lsB[2][128*32];
  const int tid = threadIdx.x, lane = tid&63, w = tid>>6;
  const int quad = lane>>4, l15 = lane&15;
  const int2 swz = xcd_swz();
  const int bn = swz.x, bm = swz.y;
  const int wm = w&1, wn = w>>1;
  fx4 acc[4][4];
  #pragma unroll
  for(int i=0;i<4;i++)
    #pragma unroll
    for(int j=0;j<4;j++) acc[i][j] = (fx4){0.f,0.f,0.f,0.f};
  const u16* Ab = A + (size_t)bm*128*K;
  const u16* Wb = W + (size_t)bn*128*K;
  KLOOP_SYNC128(Ab, Wb, K, wm*4)
  const int colbase = bn*128 + wn*64;
  float bcol[4];
  #pragma unroll
  for(int nt=0;nt<4;nt++) bcol[nt] = bias[colbase + nt*16 + l15];
  #pragma unroll
  for(int mt=0;mt<4;mt++)
    #pragma unroll
    for(int r=0;r<4;r++){
      int row = bm*128 + wm*64 + mt*16 + quad*4 + r;
      #pragma unroll
      for(int nt=0;nt<4;nt++){
        int col = colbase + nt*16 + l15;
        out[faddr(row, col, N)] = f2bf(gelu_fast(acc[mt][nt][r] + bcol[nt]));
      }
    }
}

// ---------------- ctx[i,b,h][d1][d2] = sum_t k[t][d1] v[t][d2] (MFMA over t) ----------------
__global__ __launch_bounds__(256) void ctx_kernel(const u16* __restrict__ kb,
    const u16* __restrict__ vb, float* __restrict__ ctx, size_t kstride){
  __shared__ __align__(16) u16 lk[64*72];  // transposed [d][t], stride 72
  __shared__ __align__(16) u16 lv[64*72];
  const int tid=threadIdx.x, lane=tid&63, w=tid>>6, quad=lane>>4, l15=lane&15;
  const int bh2 = blockIdx.x, i = bh2>>5, h = bh2&7, b = (bh2>>3)&3;
  const u16* kbase = kb + (size_t)i*kstride;
  const u16* vbase = vb + (size_t)i*kstride;
  const size_t rowbase = (size_t)b*4096 + (size_t)blockIdx.y*512;
  const int mt0=(w&1)*32, nt0=(w>>1)*32;
  fx4 acc[2][2];
  #pragma unroll
  for(int x=0;x<2;x++)
    #pragma unroll
    for(int j=0;j<2;j++) acc[x][j] = (fx4){0.f,0.f,0.f,0.f};
  const int tl = tid>>2, part = tid&3;
  for(int it=0; it<8; it++){
    __syncthreads();
    {
      size_t gro = (rowbase + it*64 + tl)*512 + h*64 + part*16;
      bh8 k0 = *(const bh8*)(kbase + gro); bh8 k1 = *(const bh8*)(kbase + gro + 8);
      bh8 v0 = *(const bh8*)(vbase + gro); bh8 v1 = *(const bh8*)(vbase + gro + 8);
      #pragma unroll
      for(int j=0;j<8;j++){
        lk[(part*16+j  )*72 + tl] = (u16)k0[j];
        lk[(part*16+8+j)*72 + tl] = (u16)k1[j];
        lv[(part*16+j  )*72 + tl] = (u16)v0[j];
        lv[(part*16+8+j)*72 + tl] = (u16)v1[j];
      }
    }
    __syncthreads();
    #pragma unroll
    for(int ks=0;ks<2;ks++){
      bh8 a0 = *(const bh8*)&lk[(mt0    +l15)*72 + ks*32 + quad*8];
      bh8 a1 = *(const bh8*)&lk[(mt0+16 +l15)*72 + ks*32 + quad*8];
      bh8 b0 = *(const bh8*)&lv[(nt0    +l15)*72 + ks*32 + quad*8];
      bh8 b1 = *(const bh8*)&lv[(nt0+16 +l15)*72 + ks*32 + quad*8];
      acc[0][0] = __builtin_amdgcn_mfma_f32_16x16x32_bf16(a0,b0,acc[0][0],0,0,0);
      acc[0][1] = __builtin_amdgcn_mfma_f32_16x16x32_bf16(a0,b1,acc[0][1],0,0,0);
      acc[1][0] = __builtin_amdgcn_mfma_f32_16x16x32_bf16(a1,b0,acc[1][0],0,0,0);
      acc[1][1] = __builtin_amdgcn_mfma_f32_16x16x32_bf16(a1,b1,acc[1][1],0,0,0);
    }
  }
  float* cb = ctx + (size_t)bh2*4096;
  #pragma unroll
  for(int mi=0;mi<2;mi++)
    #pragma unroll
    for(int ni=0;ni<2;ni++)
      #pragma unroll
      for(int r=0;r<4;r++){
        int d1 = mt0 + mi*16 + quad*4 + r;
        int d2 = nt0 + ni*16 + l15;
        atomicAdd(&cb[d1*64 + d2], acc[mi][ni][r]);
      }
}

// --- out = q + sum_i (q @ ctx_i)*Dinv_i; writes OUTB in FRAGMENT layout (K=512) ---
template<int NIN>
__global__ __launch_bounds__(256) void apply_kernel(const u16* __restrict__ q,
    const float* __restrict__ ctx, const float* __restrict__ ksum, float eps,
    u16* __restrict__ out){
  __shared__ __align__(16) u16 lctx[(NIN+1)*64*72];
  const int tid=threadIdx.x, lane=tid&63, w=tid>>6, quad=lane>>4, l15=lane&15;
  const int bh = blockIdx.x, b=bh>>3, h=bh&7;
  {
    int base = tid*16;
    int d1 = base>>6, d2b = base&63;
    #pragma unroll
    for(int s=0;s<=NIN;s++){
      u16* dst = &lctx[s*64*72];
      if(s<NIN){
        const float* sp = ctx + ((size_t)s*32 + bh)*4096 + base;
        #pragma unroll
        for(int j=0;j<16;j++) dst[(d2b+j)*72 + d1] = f2bf(sp[j]);
      } else {
        #pragma unroll
        for(int j=0;j<16;j++) dst[(d2b+j)*72 + d1] = ((d2b+j)==d1) ? (u16)0x3f80 : (u16)0;
      }
    }
  }
  float kslo[NIN][8], kshi[NIN][8];
  #pragma unroll
  for(int s=0;s<NIN;s++){
    const float* ks = ksum + s*2048 + b*512 + h*64;
    #pragma unroll
    for(int j=0;j<8;j++){ kslo[s][j] = ks[quad*8+j]; kshi[s][j] = ks[32+quad*8+j]; }
  }
  __syncthreads();
  bh8 bfr[NIN+1][4][2];
  #pragma unroll
  for(int s=0;s<=NIN;s++)
    #pragma unroll
    for(int nt=0;nt<4;nt++)
      #pragma unroll
      for(int ks=0;ks<2;ks++)
        bfr[s][nt][ks] = *(const bh8*)&lctx[s*64*72 + (nt*16+l15)*72 + ks*32 + quad*8];
  const size_t tb0 = (size_t)b*4096 + (size_t)blockIdx.y*256 + w*64;
  for(int g=0;g<4;g++){
    size_t tb = tb0 + g*16;
    const u16* qr = q + (tb + l15)*512 + h*64;
    bh8 a0 = *(const bh8*)(qr + quad*8);
    bh8 a1 = *(const bh8*)(qr + 32 + quad*8);
    float dv[NIN][4];
    #pragma unroll
    for(int s=0;s<NIN;s++){
      float part = 0.f;
      #pragma unroll
      for(int j=0;j<8;j++)
        part += bf2f((u16)a0[j])*kslo[s][j] + bf2f((u16)a1[j])*kshi[s][j];
      part += __shfl_xor(part,16,64); part += __shfl_xor(part,32,64);
      #pragma unroll
      for(int r=0;r<4;r++)
        dv[s][r] = __fdividef(1.f, __shfl(part, quad*4+r, 64) + eps);
    }
    fx4 outv[4];
    #pragma unroll
    for(int nt=0;nt<4;nt++) outv[nt] = (fx4){0.f,0.f,0.f,0.f};
    #pragma unroll
    for(int s=0;s<=NIN;s++){
      fx4 c[4];
      #pragma unroll
      for(int nt=0;nt<4;nt++){
        c[nt] = (fx4){0.f,0.f,0.f,0.f};
        c[nt] = __builtin_amdgcn_mfma_f32_16x16x32_bf16(a0, bfr[s][nt][0], c[nt], 0,0,0);
        c[nt] = __builtin_amdgcn_mfma_f32_16x16x32_bf16(a1, bfr[s][nt][1], c[nt], 0,0,0);
      }
      #pragma unroll
      for(int nt=0;nt<4;nt++)
        #pragma unroll
        for(int r=0;r<4;r++) outv[nt][r] += c[nt][r]*((s==NIN)?1.f:dv[s][r]);
    }
    #pragma unroll
    for(int nt=0;nt<4;nt++)
      #pragma unroll
      for(int r=0;r<4;r++)
        out[faddr((int)tb + quad*4 + r, h*64 + nt*16 + l15, 512)] = f2bf(outv[nt][r]);
  }
}

// =========================================================================
extern "C" void kernel_launch(void* const* d_in, const int* in_sizes, int n_in,
                              void* d_out, int out_size, void* d_ws, size_t ws_size,
                              hipStream_t stream){
  const float* x_in =(const float*)d_in[0];
  const float* ys   =(const float*)d_in[1];
  const float* ln1g =(const float*)d_in[2],  *ln1b=(const float*)d_in[3];
  const float* ln2g =(const float*)d_in[4],  *ln2b=(const float*)d_in[5];
  const float* ln3g =(const float*)d_in[6],  *ln3b=(const float*)d_in[7];
  const float* ln4g =(const float*)d_in[8],  *ln4b=(const float*)d_in[9];
  const float* ln5g =(const float*)d_in[10], *ln5b=(const float*)d_in[11];
  const float* ca_wq=(const float*)d_in[12], *ca_bq=(const float*)d_in[13];
  const float* ca_wk=(const float*)d_in[14], *ca_bk=(const float*)d_in[15];
  const float* ca_wv=(const float*)d_in[16], *ca_bv=(const float*)d_in[17];
  const float* ca_wo=(const float*)d_in[18], *ca_bo=(const float*)d_in[19];
  const float* sa_wq=(const float*)d_in[20], *sa_bq=(const float*)d_in[21];
  const float* sa_wk=(const float*)d_in[22], *sa_bk=(const float*)d_in[23];
  const float* sa_wv=(const float*)d_in[24], *sa_bv=(const float*)d_in[25];
  const float* sa_wo=(const float*)d_in[26], *sa_bo=(const float*)d_in[27];
  const float* f1w1 =(const float*)d_in[28], *f1b1=(const float*)d_in[29];
  const float* f1w2 =(const float*)d_in[30], *f1b2=(const float*)d_in[31];
  const float* f2w1 =(const float*)d_in[32], *f2b1=(const float*)d_in[33];
  const float* f2w2 =(const float*)d_in[34], *f2b2=(const float*)d_in[35];

  char* p = (char*)d_ws;
  u16*   WBF = (u16*)p;    p += 13631488;   // bf16 weights (row-major)
  float* XW  = (float*)p;  p += 33554432;   // residual stream fp32 [16384,512]
  u16*   XN2 = (u16*)p;    p += 33554432;   // LN out (frag layout), up to 2x16384 rows
  u16*   QB  = (u16*)p;    p += 16777216;   // q softmax out (row-major)
  u16*   R1  = (u16*)p;    p += 67108864;   // FFN hidden (frag) OR stacked KB2|VB2 (row)
  u16*   OUTB= (u16*)p;    p += 16777216;   // attn out / x-LN staging (frag layout)
  float* SM  = (float*)p;  p += 1597440;    // ctx + ksum (zeroed)
  u16*   XN  = XN2;
  u16*   KB2 = R1;
  u16*   VB2 = R1 + 16777216;
  u16*   HB  = R1;
  float* CTXC = SM;                          // [2][32][4096]
  float* CTXS = SM + 262144;                 // [32][4096]
  float* KSC  = SM + 393216;                 // [2][4][512]
  float* KSS  = SM + 397312;                 // [4][512]

  WDesc wd;
  const float* wsrc[14] = {ca_wq, ca_wk, ca_wv, ca_wk+262144, ca_wv+262144, ca_wo,
                           sa_wq, sa_wk, sa_wv, sa_wo, f1w1, f1w2, f2w1, f2w2};
  const int    woff[14] = {0, 262144, 524288, 786432, 1048576, 1310720,
                           1572864, 1835008, 2097152, 2359296,
                           2621440, 3670016, 4718592, 5767168};
  for(int i=0;i<14;i++){ wd.src[i]=wsrc[i]; wd.off[i]=woff[i]; }
  convw_kernel<<<26624,256,0,stream>>>(wd, WBF);
  hipMemsetAsync(SM, 0, 399360*sizeof(float), stream);

  SubD zsub = {nullptr,nullptr,nullptr,0};

  // ---- cross attention ----
  ln_kernel<<<4096,256,0,stream>>>(x_in, ln1g, ln1b, OUTB);   // x-LN staged (frag) in OUTB
  lny_kernel<<<8192,256,0,stream>>>(ys, ln2g, ln2b, XN2);     // both ys LNs (frag)
  gemm_q64<<<dim3(8,128),256,0,stream>>>(OUTB, WBF+0, ca_bq, QB);
  { Subs3 s = {{ {ca_bk, KB2, KSC, 1}, {ca_bv, VB2, nullptr, 0}, zsub }};
    gemm_qkv<<<dim3(8,256),256,0,stream>>>(XN2, WBF+262144, s, 512,
                                           524288, 512, 2048); }  // i = bm>>7
  ctx_kernel<<<dim3(64,8),256,0,stream>>>(KB2, VB2, CTXC, (size_t)16384*512);
  apply_kernel<2><<<dim3(32,16),256,0,stream>>>(QB, CTXC, KSC, 1e-8f, OUTB);
  gemm_dn64<<<dim3(8,128),256,0,stream>>>(OUTB, WBF+1310720, ca_bo, x_in, XW, 512, 512);

  // ---- FFN 1 ----
  ln_kernel<<<4096,256,0,stream>>>(XW, ln3g, ln3b, XN);
  gemm_up<<<dim3(16,128),256,0,stream>>>(XN, WBF+2621440, f1b1, HB, 2048, 512);
  gemm_dn64<<<dim3(8,128),256,0,stream>>>(HB, WBF+3670016, f1b2, XW, XW, 512, 2048);

  // ---- linear self attention ----
  ln_kernel<<<4096,256,0,stream>>>(XW, ln4g, ln4b, XN);
  { Subs3 s = {{ {sa_bq, QB, nullptr, 1}, {sa_bk, KB2, KSS, 1}, {sa_bv, VB2, nullptr, 0} }};
    gemm_qkv<<<dim3(12,128),256,0,stream>>>(XN, WBF+1572864, s, 512, 0,0,0); }
  ctx_kernel<<<dim3(32,8),256,0,stream>>>(KB2, VB2, CTXS, 0);
  apply_kernel<1><<<dim3(32,16),256,0,stream>>>(QB, CTXS, KSS, 0.f, OUTB);
  gemm_dn64<<<dim3(8,128),256,0,stream>>>(OUTB, WBF+2359296, sa_bo, XW, XW, 512, 512);

  // ---- FFN 2 ----
  ln_kernel<<<4096,256,0,stream>>>(XW, ln5g, ln5b, XN);
  gemm_up<<<dim3(16,128),256,0,stream>>>(XN, WBF+4718592, f2b1, HB, 2048, 512);
  gemm_dn64<<<dim3(8,128),256,0,stream>>>(HB, WBF+5767168, f2b2, XW, (float*)d_out, 512, 2048);
}

// Round 10
// 705.108 us; speedup vs baseline: 1.0616x; 1.0567x over previous
//
// CrossAttentionBlock_56813827392085 — fused transformer block, bf16 MFMA internals. R16:
//  = R12 VERBATIM (best @692us: A-reg depth-1 from frag-layout global, B via gload_lds
//  2-ring LDS + counted vmcnt(10)/(5), SYNC loop for up-proj) — R14/R15's depth-2+PIN
//  regressed (VGPR 84->104, occ 26->20%, up 62.5->78; order-pinning defeats compiler
//  scheduling, 8 rounds of schedule levers all null/negative at these shapes) —
//  + ONE change: hardware v_cvt_pk_bf16_f32 replaces paired software-RNE f2bf in the
//  three conversion-dense epilogues (gemm_up gelu, gemm_qkv softmax, gemm_q64 softmax):
//  ~4 VALU/value -> 0.5 instr/value. R12's gemm_up epilogue (~2000cy VALU/wave) rivals
//  its main loop (1230cy); VALUBusy 46% vs MfmaUtil 21.5% says epilogue VALU is the
//  residual cost. Frag-address row-base hoisted out of the nt loop.
#include <hip/hip_runtime.h>
#include <hip/hip_bf16.h>
#include <math.h>
#include <stdint.h>

typedef unsigned short u16;
typedef __attribute__((ext_vector_type(8))) short bh8;
typedef __attribute__((ext_vector_type(4))) float fx4;

#define DEV static __device__ __forceinline__

DEV float bf2f(u16 u){ union{unsigned u; float f;} v; v.u = ((unsigned)u)<<16; return v.f; }
DEV u16 f2bf(float f){ union{float f; unsigned u;} v; v.f = f;
  return (u16)((v.u + 0x7fffu + ((v.u>>16)&1u))>>16); }               // RNE

// HW packed f32->bf16 (RNE): lo16 = cvt(a), hi16 = cvt(b). 1 instr for 2 values.
DEV unsigned cvtpk(float a, float b){
  unsigned r;
  asm("v_cvt_pk_bf16_f32 %0, %1, %2" : "=v"(r) : "v"(a), "v"(b));
  return r;
}

DEV void async16(const u16* g, u16* l){
  __builtin_amdgcn_global_load_lds((__attribute__((address_space(1))) void*)(uintptr_t)g,
                                   (__attribute__((address_space(3))) void*)l, 16, 0, 0);
}

// MFMA-A fragment address for a [rows][Kbuf] bf16 buffer.
DEV size_t faddr(int row, int col, int Kbuf){
  return (size_t)(row>>4)*((size_t)Kbuf*16)
       + (size_t)((col>>3)*128 + (row&15)*8 + (col&7));
}

// gelu tanh-approx via sigmoid identity: x * 1/(1+exp(x*(-1.59577 - 0.0713548*x^2)))
DEV float gelu_fast(float x){
  float x2 = x*x;
  float t  = __builtin_fmaf(x2, -0.071354816f, -1.5957691216f);
  float e  = __expf(x*t);
  return __fdividef(x, 1.f + e);
}

// XCD-aware bijective block swizzle (requires nwg%8==0 — all GEMM grids here satisfy).
DEV int2 xcd_swz(){
  const int gx  = gridDim.x;
  const int ord = blockIdx.y*gx + blockIdx.x;
  const int nwg = gx*gridDim.y;
  const int wg  = (ord&7)*(nwg>>3) + (ord>>3);
  int2 r; r.x = wg % gx; r.y = wg / gx; return r;
}

// ---------------- weight fp32 -> bf16 pack (row-major) ----------------
struct WDesc { const float* src[14]; int off[14]; };
__global__ __launch_bounds__(256) void convw_kernel(WDesc d, u16* __restrict__ dst){
  int i = blockIdx.x*256 + threadIdx.x;
  int s = 0;
  #pragma unroll
  for(int j=1;j<14;j++) if(i >= d.off[j]) s = j;
  dst[i] = f2bf(d.src[s][i - d.off[s]]);
}

// ---------------- LayerNorm (C=512), fp32 in -> bf16 FRAGMENT-layout out ----------------
DEV float wsum64(float s){
  s += __shfl_xor(s,1,64);  s += __shfl_xor(s,2,64);  s += __shfl_xor(s,4,64);
  s += __shfl_xor(s,8,64);  s += __shfl_xor(s,16,64); s += __shfl_xor(s,32,64);
  return s;
}
DEV void ln_row(const float* xrow, const float* g, const float* bta, u16* orow, int lane){
  const float4* xr = (const float4*)xrow + lane*2;
  float4 a = xr[0], c = xr[1];
  float s = a.x+a.y+a.z+a.w + c.x+c.y+c.z+c.w;
  float mean = wsum64(s) * (1.f/512.f);
  float d0=a.x-mean,d1=a.y-mean,d2=a.z-mean,d3=a.w-mean;
  float d4=c.x-mean,d5=c.y-mean,d6=c.z-mean,d7=c.w-mean;
  float sv = d0*d0+d1*d1+d2*d2+d3*d3+d4*d4+d5*d5+d6*d6+d7*d7;
  float rstd = rsqrtf(wsum64(sv)*(1.f/512.f) + 1e-5f);
  const float4* gr = (const float4*)g   + lane*2;
  const float4* br = (const float4*)bta + lane*2;
  float4 g0=gr[0], g1=gr[1], b0=br[0], b1=br[1];
  bh8 o;
  o[0]=(short)f2bf(d0*rstd*g0.x+b0.x); o[1]=(short)f2bf(d1*rstd*g0.y+b0.y);
  o[2]=(short)f2bf(d2*rstd*g0.z+b0.z); o[3]=(short)f2bf(d3*rstd*g0.w+b0.w);
  o[4]=(short)f2bf(d4*rstd*g1.x+b1.x); o[5]=(short)f2bf(d5*rstd*g1.y+b1.y);
  o[6]=(short)f2bf(d6*rstd*g1.z+b1.z); o[7]=(short)f2bf(d7*rstd*g1.w+b1.w);
  *(bh8*)(orow + (size_t)lane*128) = o;
}
__global__ __launch_bounds__(256) void ln_kernel(const float* __restrict__ x,
    const float* __restrict__ g, const float* __restrict__ bta, u16* __restrict__ out){
  int row  = blockIdx.x*4 + (threadIdx.x>>6);
  u16* orow = out + (size_t)(row>>4)*8192 + (size_t)(row&15)*8;
  ln_row(x + (size_t)row*512, g, bta, orow, threadIdx.x&63);
}
__global__ __launch_bounds__(256) void lny_kernel(const float* __restrict__ ys,
    const float* __restrict__ g2, const float* __restrict__ b2, u16* __restrict__ out){
  int row  = blockIdx.x*4 + (threadIdx.x>>6);
  int i = row>>14;
  u16* orow = out + (size_t)(row>>4)*8192 + (size_t)(row&15)*8;
  ln_row(ys + (size_t)row*512, g2 + i*512, b2 + i*512, orow, threadIdx.x&63);
}

// ==== GEMM K-loop pieces (R12 verbatim): B staged in LDS, A direct-global frag ====
// C/D layout: out_row = quad*4+r (within 16), out_col = l15.
#define BSTAGE128(Wb, K, kk, buf)                                                    \
    async16(Wb + (size_t)srow*(K)      + (kk) + scol, &lsB[buf][(w*32   )*32]);      \
    async16(Wb + (size_t)(srow+16)*(K) + (kk) + scol, &lsB[buf][(w*32+16)*32]);

#define APREF4(AF, K, kk)                                                            \
    _Pragma("unroll")                                                                \
    for(int t=0;t<4;t++)                                                             \
      AF[t] = *(const bh8*)(Alane + (size_t)t*16*(K) + (size_t)(kk)*16);

#define MFMA128(AF, CUR)                                                             \
    { bh8 bfx[4];                                                                    \
      _Pragma("unroll")                                                              \
      for(int t=0;t<4;t++)                                                           \
        bfx[t] = *(const bh8*)&lsB[CUR][(wn*64+t*16+l15)*32 + rsw*8];                \
      _Pragma("unroll")                                                              \
      for(int mt=0;mt<4;mt++)                                                        \
        _Pragma("unroll")                                                            \
        for(int nt=0;nt<4;nt++)                                                      \
          acc[mt][nt] = __builtin_amdgcn_mfma_f32_16x16x32_bf16(AF[mt], bfx[nt], acc[mt][nt], 0,0,0); }

// counted step: ages B(j)=2(old), A(j)=4, B(j+1)=2, A(j+1)=4 -> vmcnt(10) completes B(j).
#define CSTEP128(AFU, AFP, CUR, jj, Wb, K)                                           \
    if((jj)+1<NS){                                                                   \
      BSTAGE128(Wb, K, ((jj)+1)*32, (CUR)^1)                                         \
      asm volatile("" ::: "memory");                                                 \
      APREF4(AFP, K, ((jj)+1)*32)                                                    \
      asm volatile("s_waitcnt vmcnt(10)" ::: "memory");                              \
    } else {                                                                         \
      asm volatile("s_waitcnt vmcnt(0)" ::: "memory");                               \
    }                                                                                \
    __builtin_amdgcn_s_barrier();                                                    \
    MFMA128(AFU, CUR)                                                                \
    __builtin_amdgcn_s_barrier();

#define KLOOP_CNT128(Ab, Wb, K, WTILE)                                               \
  const int srow = w*32 + (lane>>2);                                                 \
  const int scol = (((lane&3) ^ ((srow>>1)&3)) * 8);                                 \
  const int rsw  = ((l15>>1)&3) ^ quad;                                              \
  const u16* Alane = (Ab) + (size_t)(WTILE)*16*(K) + lane*8;                         \
  bh8 afA[4], afB[4];                                                                \
  BSTAGE128(Wb, K, 0, 0)                                                             \
  asm volatile("" ::: "memory");                                                     \
  APREF4(afA, K, 0)                                                                  \
  const int NS = (K)>>5;                                                             \
  for(int j=0;j<NS;j+=2){                                                            \
    CSTEP128(afA, afB, 0, j,   Wb, K)                                                \
    CSTEP128(afB, afA, 1, j+1, Wb, K)                                                \
  }

// SYNC variant (proven best for the gelu up-proj): __syncthreads drains everything.
#define SSTEP128(AFU, AFP, CUR, jj, Wb, K)                                           \
    if((jj)+1<NS){                                                                   \
      BSTAGE128(Wb, K, ((jj)+1)*32, (CUR)^1)                                         \
      APREF4(AFP, K, ((jj)+1)*32)                                                    \
    }                                                                                \
    MFMA128(AFU, CUR)                                                                \
    __syncthreads();

#define KLOOP_SYNC128(Ab, Wb, K, WTILE)                                              \
  const int srow = w*32 + (lane>>2);                                                 \
  const int scol = (((lane&3) ^ ((srow>>1)&3)) * 8);                                 \
  const int rsw  = ((l15>>1)&3) ^ quad;                                              \
  const u16* Alane = (Ab) + (size_t)(WTILE)*16*(K) + lane*8;                         \
  bh8 afA[4], afB[4];                                                                \
  BSTAGE128(Wb, K, 0, 0)                                                             \
  APREF4(afA, K, 0)                                                                  \
  __syncthreads();                                                                   \
  const int NS = (K)>>5;                                                             \
  for(int j=0;j<NS;j+=2){                                                            \
    SSTEP128(afA, afB, 0, j,   Wb, K)                                                \
    SSTEP128(afB, afA, 1, j+1, Wb, K)                                                \
  }

// BN=64: 4 waves stacked in M (each 32 rows x 64 cols). B stage=1, A loads=2 -> vmcnt(5).
#define BSTAGE64(Wb, K, kk, buf)                                                     \
    async16(Wb + (size_t)browB*(K) + (kk) + scolB, &lsB[buf][(w*16)*32]);

#define APREF2(AF, K, kk)                                                            \
    _Pragma("unroll")                                                                \
    for(int t=0;t<2;t++)                                                             \
      AF[t] = *(const bh8*)(Alane + (size_t)t*16*(K) + (size_t)(kk)*16);

#define MFMA64(AF, CUR)                                                              \
    { bh8 bfx[4];                                                                    \
      _Pragma("unroll")                                                              \
      for(int t=0;t<4;t++)                                                           \
        bfx[t] = *(const bh8*)&lsB[CUR][(t*16+l15)*32 + rsw*8];                      \
      _Pragma("unroll")                                                              \
      for(int mt=0;mt<2;mt++)                                                        \
        _Pragma("unroll")                                                            \
        for(int nt=0;nt<4;nt++)                                                      \
          acc[mt][nt] = __builtin_amdgcn_mfma_f32_16x16x32_bf16(AF[mt], bfx[nt], acc[mt][nt], 0,0,0); }

#define CSTEP64(AFU, AFP, CUR, jj, Wb, K)                                            \
    if((jj)+1<NS){                                                                   \
      BSTAGE64(Wb, K, ((jj)+1)*32, (CUR)^1)                                          \
      asm volatile("" ::: "memory");                                                 \
      APREF2(AFP, K, ((jj)+1)*32)                                                    \
      asm volatile("s_waitcnt vmcnt(5)" ::: "memory");                               \
    } else {                                                                         \
      asm volatile("s_waitcnt vmcnt(0)" ::: "memory");                               \
    }                                                                                \
    __builtin_amdgcn_s_barrier();                                                    \
    MFMA64(AFU, CUR)                                                                 \
    __builtin_amdgcn_s_barrier();

#define KLOOP_CNT64(Ab, Wb, K)                                                       \
  const int browB = w*16 + (lane>>2);                                                \
  const int scolB = (((lane&3) ^ ((browB>>1)&3)) * 8);                               \
  const int rsw   = ((l15>>1)&3) ^ quad;                                             \
  const u16* Alane = (Ab) + (size_t)(w*2)*16*(K) + lane*8;                           \
  bh8 afA[2], afB[2];                                                                \
  BSTAGE64(Wb, K, 0, 0)                                                              \
  asm volatile("" ::: "memory");                                                     \
  APREF2(afA, K, 0)                                                                  \
  const int NS = (K)>>5;                                                             \
  for(int j=0;j<NS;j+=2){                                                            \
    CSTEP64(afA, afB, 0, j,   Wb, K)                                                 \
    CSTEP64(afB, afA, 1, j+1, Wb, K)                                                 \
  }

// ---------------- multi-output projection GEMM (BN=128, A frag-layout) ----------------
struct SubD { const float* bias; u16* out; float* ksum; int mode; };
struct Subs3 { SubD s[3]; };
__global__ __launch_bounds__(256) void gemm_qkv(const u16* __restrict__ A,
    const u16* __restrict__ W, Subs3 subs, int K, int wstride, int bstride, int ksstride){
  __shared__ __align__(16) u16 lsB[2][128*32];
  const int tid = threadIdx.x, lane = tid&63, w = tid>>6;
  const int quad = lane>>4, l15 = lane&15;
  const int2 swz = xcd_swz();
  const int bn = swz.x, bm = swz.y;
  const int iset = bm>>7;
  const int wm = w&1, wn = w>>1;
  fx4 acc[4][4];
  #pragma unroll
  for(int i=0;i<4;i++)
    #pragma unroll
    for(int j=0;j<4;j++) acc[i][j] = (fx4){0.f,0.f,0.f,0.f};
  const u16* Ab = A + (size_t)bm*128*K;      // == frag tile (bm*8) base
  const u16* Wb = W + (size_t)iset*wstride + (size_t)bn*128*K;
  KLOOP_CNT128(Ab, Wb, K, wm*4)
  const SubD sub = subs.s[bn>>2];
  const int colw = (bn&3)*128 + wn*64;
  const float* bias = sub.bias + iset*bstride;
  float bcol[4];
  #pragma unroll
  for(int nt=0;nt<4;nt++) bcol[nt] = bias[colw + nt*16 + l15];

  if(sub.mode==1){
    float ksacc[4] = {0.f,0.f,0.f,0.f};
    #pragma unroll
    for(int mt=0;mt<4;mt++)
      #pragma unroll
      for(int r=0;r<4;r++){
        float v0=acc[mt][0][r]+bcol[0], v1=acc[mt][1][r]+bcol[1];
        float v2=acc[mt][2][r]+bcol[2], v3=acc[mt][3][r]+bcol[3];
        float mx = fmaxf(fmaxf(v0,v1),fmaxf(v2,v3));
        mx = fmaxf(mx,__shfl_xor(mx,1,64)); mx = fmaxf(mx,__shfl_xor(mx,2,64));
        mx = fmaxf(mx,__shfl_xor(mx,4,64)); mx = fmaxf(mx,__shfl_xor(mx,8,64));
        float e0=__expf(v0-mx), e1=__expf(v1-mx), e2=__expf(v2-mx), e3=__expf(v3-mx);
        float s = e0+e1+e2+e3;
        s += __shfl_xor(s,1,64); s += __shfl_xor(s,2,64);
        s += __shfl_xor(s,4,64); s += __shfl_xor(s,8,64);
        float inv = __fdividef(1.f, s);
        e0*=inv; e1*=inv; e2*=inv; e3*=inv;
        ksacc[0]+=e0; ksacc[1]+=e1; ksacc[2]+=e2; ksacc[3]+=e3;
        int row = bm*128 + wm*64 + mt*16 + quad*4 + r;
        size_t rb = (size_t)row*512;
        unsigned p01 = cvtpk(e0,e1), p23 = cvtpk(e2,e3);
        sub.out[rb+colw+ 0+l15]=(u16)p01; sub.out[rb+colw+16+l15]=(u16)(p01>>16);
        sub.out[rb+colw+32+l15]=(u16)p23; sub.out[rb+colw+48+l15]=(u16)(p23>>16);
      }
    if(sub.ksum){
      int b = (bm&127)>>5;
      float* ks = sub.ksum + iset*ksstride + b*512;
      #pragma unroll
      for(int nt=0;nt<4;nt++){
        float s = ksacc[nt];
        s += __shfl_xor(s,16,64); s += __shfl_xor(s,32,64);
        if(quad==0) atomicAdd(&ks[colw + nt*16 + l15], s);
      }
    }
  } else {
    #pragma unroll
    for(int mt=0;mt<4;mt++)
      #pragma unroll
      for(int r=0;r<4;r++){
        int row = bm*128 + wm*64 + mt*16 + quad*4 + r;
        size_t rb = (size_t)row*512;
        unsigned p01 = cvtpk(acc[mt][0][r]+bcol[0], acc[mt][1][r]+bcol[1]);
        unsigned p23 = cvtpk(acc[mt][2][r]+bcol[2], acc[mt][3][r]+bcol[3]);
        sub.out[rb+colw+ 0+l15]=(u16)p01; sub.out[rb+colw+16+l15]=(u16)(p01>>16);
        sub.out[rb+colw+32+l15]=(u16)p23; sub.out[rb+colw+48+l15]=(u16)(p23>>16);
      }
  }
}

// ---------------- CA q-proj (BN=64): softmax epilogue, grid (8,128) ----------------
__global__ __launch_bounds__(256) void gemm_q64(const u16* __restrict__ A,
    const u16* __restrict__ W, const float* __restrict__ bias, u16* __restrict__ out){
  __shared__ __align__(16) u16 lsB[2][64*32];
  const int tid = threadIdx.x, lane = tid&63, w = tid>>6;
  const int quad = lane>>4, l15 = lane&15;
  const int2 swz = xcd_swz();
  const int bn = swz.x, bm = swz.y;
  fx4 acc[2][4];
  #pragma unroll
  for(int i=0;i<2;i++)
    #pragma unroll
    for(int j=0;j<4;j++) acc[i][j] = (fx4){0.f,0.f,0.f,0.f};
  const u16* Ab = A + (size_t)bm*128*512;
  const u16* Wb = W + (size_t)bn*64*512;
  KLOOP_CNT64(Ab, Wb, 512)
  const int colb = bn*64;
  float bcol[4];
  #pragma unroll
  for(int nt=0;nt<4;nt++) bcol[nt] = bias[colb + nt*16 + l15];
  #pragma unroll
  for(int mt=0;mt<2;mt++)
    #pragma unroll
    for(int r=0;r<4;r++){
      float v0=acc[mt][0][r]+bcol[0], v1=acc[mt][1][r]+bcol[1];
      float v2=acc[mt][2][r]+bcol[2], v3=acc[mt][3][r]+bcol[3];
      float mx = fmaxf(fmaxf(v0,v1),fmaxf(v2,v3));
      mx = fmaxf(mx,__shfl_xor(mx,1,64)); mx = fmaxf(mx,__shfl_xor(mx,2,64));
      mx = fmaxf(mx,__shfl_xor(mx,4,64)); mx = fmaxf(mx,__shfl_xor(mx,8,64));
      float e0=__expf(v0-mx), e1=__expf(v1-mx), e2=__expf(v2-mx), e3=__expf(v3-mx);
      float s = e0+e1+e2+e3;
      s += __shfl_xor(s,1,64); s += __shfl_xor(s,2,64);
      s += __shfl_xor(s,4,64); s += __shfl_xor(s,8,64);
      float inv = __fdividef(1.f, s);
      e0*=inv; e1*=inv; e2*=inv; e3*=inv;
      int row = bm*128 + w*32 + mt*16 + quad*4 + r;
      size_t rb = (size_t)row*512;
      unsigned p01 = cvtpk(e0,e1), p23 = cvtpk(e2,e3);
      out[rb+colb+ 0+l15]=(u16)p01; out[rb+colb+16+l15]=(u16)(p01>>16);
      out[rb+colb+32+l15]=(u16)p23; out[rb+colb+48+l15]=(u16)(p23>>16);
    }
}

// -------- out/down-proj (BN=64): C = A*W^T + bias + res -> fp32 row-major --------
__global__ __launch_bounds__(256) void gemm_dn64(const u16* __restrict__ A,
    const u16* __restrict__ W, const float* __restrict__ bias,
    const float* __restrict__ res, float* __restrict__ out, int N, int K){
  __shared__ __align__(16) u16 lsB[2][64*32];
  const int tid = threadIdx.x, lane = tid&63, w = tid>>6;
  const int quad = lane>>4, l15 = lane&15;
  const int2 swz = xcd_swz();
  const int bn = swz.x, bm = swz.y;
  fx4 acc[2][4];
  #pragma unroll
  for(int i=0;i<2;i++)
    #pragma unroll
    for(int j=0;j<4;j++) acc[i][j] = (fx4){0.f,0.f,0.f,0.f};
  const u16* Ab = A + (size_t)bm*128*K;
  const u16* Wb = W + (size_t)bn*64*K;
  KLOOP_CNT64(Ab, Wb, K)
  const int colb = bn*64;
  float bcol[4];
  #pragma unroll
  for(int nt=0;nt<4;nt++) bcol[nt] = bias[colb + nt*16 + l15];
  #pragma unroll
  for(int mt=0;mt<2;mt++)
    #pragma unroll
    for(int r=0;r<4;r++){
      int row = bm*128 + w*32 + mt*16 + quad*4 + r;
      size_t rb = (size_t)row*N;
      #pragma unroll
      for(int nt=0;nt<4;nt++){
        int col = colb + nt*16 + l15;
        out[rb+col] = res[rb+col] + acc[mt][nt][r] + bcol[nt];
      }
    }
}

// ------- FFN up-proj: C = A*W^T + bias -> gelu -> bf16 FRAGMENT layout (SYNC loop) -------
__global__ __launch_bounds__(256) void gemm_up(const u16* __restrict__ A,
    const u16* __restrict__ W, const float* __restrict__ bias,
    u16* __restrict__ out, int N, int K){
  __shared__ __align__(16) u16 lsB[2][128*32];
  const int tid = threadIdx.x, lane = tid&63, w = tid>>6;
  const int quad = lane>>4, l15 = lane&15;
  const int2 swz = xcd_swz();
  const int bn = swz.x, bm = swz.y;
  const int wm = w&1, wn = w>>1;
  fx4 acc[4][4];
  #pragma unroll
  for(int i=0;i<4;i++)
    #pragma unroll
    for(int j=0;j<4;j++) acc[i][j] = (fx4){0.f,0.f,0.f,0.f};
  const u16* Ab = A + (size_t)bm*128*K;
  const u16* Wb = W + (size_t)bn*128*K;
  KLOOP_SYNC128(Ab, Wb, K, wm*4)
  const int colbase = bn*128 + wn*64;
  float bcol[4];
  #pragma unroll
  for(int nt=0;nt<4;nt++) bcol[nt] = bias[colbase + nt*16 + l15];
  // frag-layout write, base hoisted: nt stride = (16 cols>>3)*128 = 256 u16.
  #pragma unroll
  for(int mt=0;mt<4;mt++)
    #pragma unroll
    for(int r=0;r<4;r++){
      int row = bm*128 + wm*64 + mt*16 + quad*4 + r;
      u16* ob = out + (size_t)(row>>4)*((size_t)N*16) + (size_t)(row&15)*8
              + (size_t)((colbase>>3) + (l15>>3))*128 + (l15&7);
      float g0 = gelu_fast(acc[mt][0][r] + bcol[0]);
      float g1 = gelu_fast(acc[mt][1][r] + bcol[1]);
      float g2 = gelu_fast(acc[mt][2][r] + bcol[2]);
      float g3 = gelu_fast(acc[mt][3][r] + bcol[3]);
      unsigned p01 = cvtpk(g0,g1), p23 = cvtpk(g2,g3);
      ob[0]   = (u16)p01; ob[256] = (u16)(p01>>16);
      ob[512] = (u16)p23; ob[768] = (u16)(p23>>16);
    }
}

// ---------------- ctx[i,b,h][d1][d2] = sum_t k[t][d1] v[t][d2] (MFMA over t) ----------------
__global__ __launch_bounds__(256) void ctx_kernel(const u16* __restrict__ kb,
    const u16* __restrict__ vb, float* __restrict__ ctx, size_t kstride){
  __shared__ __align__(16) u16 lk[64*72];  // transposed [d][t], stride 72
  __shared__ __align__(16) u16 lv[64*72];
  const int tid=threadIdx.x, lane=tid&63, w=tid>>6, quad=lane>>4, l15=lane&15;
  const int bh2 = blockIdx.x, i = bh2>>5, h = bh2&7, b = (bh2>>3)&3;
  const u16* kbase = kb + (size_t)i*kstride;
  const u16* vbase = vb + (size_t)i*kstride;
  const size_t rowbase = (size_t)b*4096 + (size_t)blockIdx.y*512;
  const int mt0=(w&1)*32, nt0=(w>>1)*32;
  fx4 acc[2][2];
  #pragma unroll
  for(int x=0;x<2;x++)
    #pragma unroll
    for(int j=0;j<2;j++) acc[x][j] = (fx4){0.f,0.f,0.f,0.f};
  const int tl = tid>>2, part = tid&3;
  for(int it=0; it<8; it++){
    __syncthreads();
    {
      size_t gro = (rowbase + it*64 + tl)*512 + h*64 + part*16;
      bh8 k0 = *(const bh8*)(kbase + gro); bh8 k1 = *(const bh8*)(kbase + gro + 8);
      bh8 v0 = *(const bh8*)(vbase + gro); bh8 v1 = *(const bh8*)(vbase + gro + 8);
      #pragma unroll
      for(int j=0;j<8;j++){
        lk[(part*16+j  )*72 + tl] = (u16)k0[j];
        lk[(part*16+8+j)*72 + tl] = (u16)k1[j];
        lv[(part*16+j  )*72 + tl] = (u16)v0[j];
        lv[(part*16+8+j)*72 + tl] = (u16)v1[j];
      }
    }
    __syncthreads();
    #pragma unroll
    for(int ks=0;ks<2;ks++){
      bh8 a0 = *(const bh8*)&lk[(mt0    +l15)*72 + ks*32 + quad*8];
      bh8 a1 = *(const bh8*)&lk[(mt0+16 +l15)*72 + ks*32 + quad*8];
      bh8 b0 = *(const bh8*)&lv[(nt0    +l15)*72 + ks*32 + quad*8];
      bh8 b1 = *(const bh8*)&lv[(nt0+16 +l15)*72 + ks*32 + quad*8];
      acc[0][0] = __builtin_amdgcn_mfma_f32_16x16x32_bf16(a0,b0,acc[0][0],0,0,0);
      acc[0][1] = __builtin_amdgcn_mfma_f32_16x16x32_bf16(a0,b1,acc[0][1],0,0,0);
      acc[1][0] = __builtin_amdgcn_mfma_f32_16x16x32_bf16(a1,b0,acc[1][0],0,0,0);
      acc[1][1] = __builtin_amdgcn_mfma_f32_16x16x32_bf16(a1,b1,acc[1][1],0,0,0);
    }
  }
  float* cb = ctx + (size_t)bh2*4096;
  #pragma unroll
  for(int mi=0;mi<2;mi++)
    #pragma unroll
    for(int ni=0;ni<2;ni++)
      #pragma unroll
      for(int r=0;r<4;r++){
        int d1 = mt0 + mi*16 + quad*4 + r;
        int d2 = nt0 + ni*16 + l15;
        atomicAdd(&cb[d1*64 + d2], acc[mi][ni][r]);
      }
}

// --- out = q + sum_i (q @ ctx_i)*Dinv_i; writes OUTB in FRAGMENT layout (K=512) ---
template<int NIN>
__global__ __launch_bounds__(256) void apply_kernel(const u16* __restrict__ q,
    const float* __restrict__ ctx, const float* __restrict__ ksum, float eps,
    u16* __restrict__ out){
  __shared__ __align__(16) u16 lctx[(NIN+1)*64*72];
  const int tid=threadIdx.x, lane=tid&63, w=tid>>6, quad=lane>>4, l15=lane&15;
  const int bh = blockIdx.x, b=bh>>3, h=bh&7;
  {
    int base = tid*16;
    int d1 = base>>6, d2b = base&63;
    #pragma unroll
    for(int s=0;s<=NIN;s++){
      u16* dst = &lctx[s*64*72];
      if(s<NIN){
        const float* sp = ctx + ((size_t)s*32 + bh)*4096 + base;
        #pragma unroll
        for(int j=0;j<16;j++) dst[(d2b+j)*72 + d1] = f2bf(sp[j]);
      } else {
        #pragma unroll
        for(int j=0;j<16;j++) dst[(d2b+j)*72 + d1] = ((d2b+j)==d1) ? (u16)0x3f80 : (u16)0;
      }
    }
  }
  float kslo[NIN][8], kshi[NIN][8];
  #pragma unroll
  for(int s=0;s<NIN;s++){
    const float* ks = ksum + s*2048 + b*512 + h*64;
    #pragma unroll
    for(int j=0;j<8;j++){ kslo[s][j] = ks[quad*8+j]; kshi[s][j] = ks[32+quad*8+j]; }
  }
  __syncthreads();
  bh8 bfr[NIN+1][4][2];
  #pragma unroll
  for(int s=0;s<=NIN;s++)
    #pragma unroll
    for(int nt=0;nt<4;nt++)
      #pragma unroll
      for(int ks=0;ks<2;ks++)
        bfr[s][nt][ks] = *(const bh8*)&lctx[s*64*72 + (nt*16+l15)*72 + ks*32 + quad*8];
  const size_t tb0 = (size_t)b*4096 + (size_t)blockIdx.y*256 + w*64;
  for(int g=0;g<4;g++){
    size_t tb = tb0 + g*16;
    const u16* qr = q + (tb + l15)*512 + h*64;
    bh8 a0 = *(const bh8*)(qr + quad*8);
    bh8 a1 = *(const bh8*)(qr + 32 + quad*8);
    float dv[NIN][4];
    #pragma unroll
    for(int s=0;s<NIN;s++){
      float part = 0.f;
      #pragma unroll
      for(int j=0;j<8;j++)
        part += bf2f((u16)a0[j])*kslo[s][j] + bf2f((u16)a1[j])*kshi[s][j];
      part += __shfl_xor(part,16,64); part += __shfl_xor(part,32,64);
      #pragma unroll
      for(int r=0;r<4;r++)
        dv[s][r] = __fdividef(1.f, __shfl(part, quad*4+r, 64) + eps);
    }
    fx4 outv[4];
    #pragma unroll
    for(int nt=0;nt<4;nt++) outv[nt] = (fx4){0.f,0.f,0.f,0.f};
    #pragma unroll
    for(int s=0;s<=NIN;s++){
      fx4 c[4];
      #pragma unroll
      for(int nt=0;nt<4;nt++){
        c[nt] = (fx4){0.f,0.f,0.f,0.f};
        c[nt] = __builtin_amdgcn_mfma_f32_16x16x32_bf16(a0, bfr[s][nt][0], c[nt], 0,0,0);
        c[nt] = __builtin_amdgcn_mfma_f32_16x16x32_bf16(a1, bfr[s][nt][1], c[nt], 0,0,0);
      }
      #pragma unroll
      for(int nt=0;nt<4;nt++)
        #pragma unroll
        for(int r=0;r<4;r++) outv[nt][r] += c[nt][r]*((s==NIN)?1.f:dv[s][r]);
    }
    #pragma unroll
    for(int nt=0;nt<4;nt++)
      #pragma unroll
      for(int r=0;r<4;r++)
        out[faddr((int)tb + quad*4 + r, h*64 + nt*16 + l15, 512)] = f2bf(outv[nt][r]);
  }
}

// =========================================================================
extern "C" void kernel_launch(void* const* d_in, const int* in_sizes, int n_in,
                              void* d_out, int out_size, void* d_ws, size_t ws_size,
                              hipStream_t stream){
  const float* x_in =(const float*)d_in[0];
  const float* ys   =(const float*)d_in[1];
  const float* ln1g =(const float*)d_in[2],  *ln1b=(const float*)d_in[3];
  const float* ln2g =(const float*)d_in[4],  *ln2b=(const float*)d_in[5];
  const float* ln3g =(const float*)d_in[6],  *ln3b=(const float*)d_in[7];
  const float* ln4g =(const float*)d_in[8],  *ln4b=(const float*)d_in[9];
  const float* ln5g =(const float*)d_in[10], *ln5b=(const float*)d_in[11];
  const float* ca_wq=(const float*)d_in[12], *ca_bq=(const float*)d_in[13];
  const float* ca_wk=(const float*)d_in[14], *ca_bk=(const float*)d_in[15];
  const float* ca_wv=(const float*)d_in[16], *ca_bv=(const float*)d_in[17];
  const float* ca_wo=(const float*)d_in[18], *ca_bo=(const float*)d_in[19];
  const float* sa_wq=(const float*)d_in[20], *sa_bq=(const float*)d_in[21];
  const float* sa_wk=(const float*)d_in[22], *sa_bk=(const float*)d_in[23];
  const float* sa_wv=(const float*)d_in[24], *sa_bv=(const float*)d_in[25];
  const float* sa_wo=(const float*)d_in[26], *sa_bo=(const float*)d_in[27];
  const float* f1w1 =(const float*)d_in[28], *f1b1=(const float*)d_in[29];
  const float* f1w2 =(const float*)d_in[30], *f1b2=(const float*)d_in[31];
  const float* f2w1 =(const float*)d_in[32], *f2b1=(const float*)d_in[33];
  const float* f2w2 =(const float*)d_in[34], *f2b2=(const float*)d_in[35];

  char* p = (char*)d_ws;
  u16*   WBF = (u16*)p;    p += 13631488;   // bf16 weights (row-major)
  float* XW  = (float*)p;  p += 33554432;   // residual stream fp32 [16384,512]
  u16*   XN2 = (u16*)p;    p += 33554432;   // LN out (frag layout), up to 2x16384 rows
  u16*   QB  = (u16*)p;    p += 16777216;   // q softmax out (row-major)
  u16*   R1  = (u16*)p;    p += 67108864;   // FFN hidden (frag) OR stacked KB2|VB2 (row)
  u16*   OUTB= (u16*)p;    p += 16777216;   // attn out / x-LN staging (frag layout)
  float* SM  = (float*)p;  p += 1597440;    // ctx + ksum (zeroed)
  u16*   XN  = XN2;
  u16*   KB2 = R1;
  u16*   VB2 = R1 + 16777216;
  u16*   HB  = R1;
  float* CTXC = SM;                          // [2][32][4096]
  float* CTXS = SM + 262144;                 // [32][4096]
  float* KSC  = SM + 393216;                 // [2][4][512]
  float* KSS  = SM + 397312;                 // [4][512]

  WDesc wd;
  const float* wsrc[14] = {ca_wq, ca_wk, ca_wv, ca_wk+262144, ca_wv+262144, ca_wo,
                           sa_wq, sa_wk, sa_wv, sa_wo, f1w1, f1w2, f2w1, f2w2};
  const int    woff[14] = {0, 262144, 524288, 786432, 1048576, 1310720,
                           1572864, 1835008, 2097152, 2359296,
                           2621440, 3670016, 4718592, 5767168};
  for(int i=0;i<14;i++){ wd.src[i]=wsrc[i]; wd.off[i]=woff[i]; }
  convw_kernel<<<26624,256,0,stream>>>(wd, WBF);
  hipMemsetAsync(SM, 0, 399360*sizeof(float), stream);

  SubD zsub = {nullptr,nullptr,nullptr,0};

  // ---- cross attention ----
  ln_kernel<<<4096,256,0,stream>>>(x_in, ln1g, ln1b, OUTB);   // x-LN staged (frag) in OUTB
  lny_kernel<<<8192,256,0,stream>>>(ys, ln2g, ln2b, XN2);     // both ys LNs (frag)
  gemm_q64<<<dim3(8,128),256,0,stream>>>(OUTB, WBF+0, ca_bq, QB);
  { Subs3 s = {{ {ca_bk, KB2, KSC, 1}, {ca_bv, VB2, nullptr, 0}, zsub }};
    gemm_qkv<<<dim3(8,256),256,0,stream>>>(XN2, WBF+262144, s, 512,
                                           524288, 512, 2048); }  // i = bm>>7
  ctx_kernel<<<dim3(64,8),256,0,stream>>>(KB2, VB2, CTXC, (size_t)16384*512);
  apply_kernel<2><<<dim3(32,16),256,0,stream>>>(QB, CTXC, KSC, 1e-8f, OUTB);
  gemm_dn64<<<dim3(8,128),256,0,stream>>>(OUTB, WBF+1310720, ca_bo, x_in, XW, 512, 512);

  // ---- FFN 1 ----
  ln_kernel<<<4096,256,0,stream>>>(XW, ln3g, ln3b, XN);
  gemm_up<<<dim3(16,128),256,0,stream>>>(XN, WBF+2621440, f1b1, HB, 2048, 512);
  gemm_dn64<<<dim3(8,128),256,0,stream>>>(HB, WBF+3670016, f1b2, XW, XW, 512, 2048);

  // ---- linear self attention ----
  ln_kernel<<<4096,256,0,stream>>>(XW, ln4g, ln4b, XN);
  { Subs3 s = {{ {sa_bq, QB, nullptr, 1}, {sa_bk, KB2, KSS, 1}, {sa_bv, VB2, nullptr, 0} }};
    gemm_qkv<<<dim3(12,128),256,0,stream>>>(XN, WBF+1572864, s, 512, 0,0,0); }
  ctx_kernel<<<dim3(32,8),256,0,stream>>>(KB2, VB2, CTXS, 0);
  apply_kernel<1><<<dim3(32,16),256,0,stream>>>(QB, CTXS, KSS, 0.f, OUTB);
  gemm_dn64<<<dim3(8,128),256,0,stream>>>(OUTB, WBF+2359296, sa_bo, XW, XW, 512, 512);

  // ---- FFN 2 ----
  ln_kernel<<<4096,256,0,stream>>>(XW, ln5g, ln5b, XN);
  gemm_up<<<dim3(16,128),256,0,stream>>>(XN, WBF+4718592, f2b1, HB, 2048, 512);
  gemm_dn64<<<dim3(8,128),256,0,stream>>>(HB, WBF+5767168, f2b2, XW, (float*)d_out, 512, 2048);
}

// Round 11
// 688.299 us; speedup vs baseline: 1.0875x; 1.0244x over previous
//
// CrossAttentionBlock_56813827392085 — fused transformer block, bf16 MFMA internals. R17:
//  = R12 VERBATIM (best @692us) + ONLY the measured-positive piece of R16:
//  gemm_up keeps v_cvt_pk_bf16_f32 + hoisted frag-store base (within-round 62.5->60.6us).
//  gemm_qkv / gemm_q64 softmax epilogues REVERTED to R12's f2bf — R16's cvtpk there cost
//  ~17us net (inline-asm operand pinning perturbed softmax regalloc; rule: co-located asm
//  perturbs codegen in large kernels — keep it only where the A/B was positive).
//  Session summary baked in: XCD swizzle + dbuf + counted-vmcnt + sigmoid-gelu + A-frag
//  direct-global are the proven wins; occupancy/no-LDS/depth-2/pinning all null/negative.
#include <hip/hip_runtime.h>
#include <hip/hip_bf16.h>
#include <math.h>
#include <stdint.h>

typedef unsigned short u16;
typedef __attribute__((ext_vector_type(8))) short bh8;
typedef __attribute__((ext_vector_type(4))) float fx4;

#define DEV static __device__ __forceinline__

DEV float bf2f(u16 u){ union{unsigned u; float f;} v; v.u = ((unsigned)u)<<16; return v.f; }
DEV u16 f2bf(float f){ union{float f; unsigned u;} v; v.f = f;
  return (u16)((v.u + 0x7fffu + ((v.u>>16)&1u))>>16); }               // RNE

// HW packed f32->bf16 (RNE): lo16 = cvt(a), hi16 = cvt(b). Used ONLY in gemm_up.
DEV unsigned cvtpk(float a, float b){
  unsigned r;
  asm("v_cvt_pk_bf16_f32 %0, %1, %2" : "=v"(r) : "v"(a), "v"(b));
  return r;
}

DEV void async16(const u16* g, u16* l){
  __builtin_amdgcn_global_load_lds((__attribute__((address_space(1))) void*)(uintptr_t)g,
                                   (__attribute__((address_space(3))) void*)l, 16, 0, 0);
}

// MFMA-A fragment address for a [rows][Kbuf] bf16 buffer.
DEV size_t faddr(int row, int col, int Kbuf){
  return (size_t)(row>>4)*((size_t)Kbuf*16)
       + (size_t)((col>>3)*128 + (row&15)*8 + (col&7));
}

// gelu tanh-approx via sigmoid identity: x * 1/(1+exp(x*(-1.59577 - 0.0713548*x^2)))
DEV float gelu_fast(float x){
  float x2 = x*x;
  float t  = __builtin_fmaf(x2, -0.071354816f, -1.5957691216f);
  float e  = __expf(x*t);
  return __fdividef(x, 1.f + e);
}

// XCD-aware bijective block swizzle (requires nwg%8==0 — all GEMM grids here satisfy).
DEV int2 xcd_swz(){
  const int gx  = gridDim.x;
  const int ord = blockIdx.y*gx + blockIdx.x;
  const int nwg = gx*gridDim.y;
  const int wg  = (ord&7)*(nwg>>3) + (ord>>3);
  int2 r; r.x = wg % gx; r.y = wg / gx; return r;
}

// ---------------- weight fp32 -> bf16 pack (row-major) ----------------
struct WDesc { const float* src[14]; int off[14]; };
__global__ __launch_bounds__(256) void convw_kernel(WDesc d, u16* __restrict__ dst){
  int i = blockIdx.x*256 + threadIdx.x;
  int s = 0;
  #pragma unroll
  for(int j=1;j<14;j++) if(i >= d.off[j]) s = j;
  dst[i] = f2bf(d.src[s][i - d.off[s]]);
}

// ---------------- LayerNorm (C=512), fp32 in -> bf16 FRAGMENT-layout out ----------------
DEV float wsum64(float s){
  s += __shfl_xor(s,1,64);  s += __shfl_xor(s,2,64);  s += __shfl_xor(s,4,64);
  s += __shfl_xor(s,8,64);  s += __shfl_xor(s,16,64); s += __shfl_xor(s,32,64);
  return s;
}
DEV void ln_row(const float* xrow, const float* g, const float* bta, u16* orow, int lane){
  const float4* xr = (const float4*)xrow + lane*2;
  float4 a = xr[0], c = xr[1];
  float s = a.x+a.y+a.z+a.w + c.x+c.y+c.z+c.w;
  float mean = wsum64(s) * (1.f/512.f);
  float d0=a.x-mean,d1=a.y-mean,d2=a.z-mean,d3=a.w-mean;
  float d4=c.x-mean,d5=c.y-mean,d6=c.z-mean,d7=c.w-mean;
  float sv = d0*d0+d1*d1+d2*d2+d3*d3+d4*d4+d5*d5+d6*d6+d7*d7;
  float rstd = rsqrtf(wsum64(sv)*(1.f/512.f) + 1e-5f);
  const float4* gr = (const float4*)g   + lane*2;
  const float4* br = (const float4*)bta + lane*2;
  float4 g0=gr[0], g1=gr[1], b0=br[0], b1=br[1];
  bh8 o;
  o[0]=(short)f2bf(d0*rstd*g0.x+b0.x); o[1]=(short)f2bf(d1*rstd*g0.y+b0.y);
  o[2]=(short)f2bf(d2*rstd*g0.z+b0.z); o[3]=(short)f2bf(d3*rstd*g0.w+b0.w);
  o[4]=(short)f2bf(d4*rstd*g1.x+b1.x); o[5]=(short)f2bf(d5*rstd*g1.y+b1.y);
  o[6]=(short)f2bf(d6*rstd*g1.z+b1.z); o[7]=(short)f2bf(d7*rstd*g1.w+b1.w);
  *(bh8*)(orow + (size_t)lane*128) = o;
}
__global__ __launch_bounds__(256) void ln_kernel(const float* __restrict__ x,
    const float* __restrict__ g, const float* __restrict__ bta, u16* __restrict__ out){
  int row  = blockIdx.x*4 + (threadIdx.x>>6);
  u16* orow = out + (size_t)(row>>4)*8192 + (size_t)(row&15)*8;
  ln_row(x + (size_t)row*512, g, bta, orow, threadIdx.x&63);
}
__global__ __launch_bounds__(256) void lny_kernel(const float* __restrict__ ys,
    const float* __restrict__ g2, const float* __restrict__ b2, u16* __restrict__ out){
  int row  = blockIdx.x*4 + (threadIdx.x>>6);
  int i = row>>14;
  u16* orow = out + (size_t)(row>>4)*8192 + (size_t)(row&15)*8;
  ln_row(ys + (size_t)row*512, g2 + i*512, b2 + i*512, orow, threadIdx.x&63);
}

// ==== GEMM K-loop pieces (R12 verbatim): B staged in LDS, A direct-global frag ====
// C/D layout: out_row = quad*4+r (within 16), out_col = l15.
#define BSTAGE128(Wb, K, kk, buf)                                                    \
    async16(Wb + (size_t)srow*(K)      + (kk) + scol, &lsB[buf][(w*32   )*32]);      \
    async16(Wb + (size_t)(srow+16)*(K) + (kk) + scol, &lsB[buf][(w*32+16)*32]);

#define APREF4(AF, K, kk)                                                            \
    _Pragma("unroll")                                                                \
    for(int t=0;t<4;t++)                                                             \
      AF[t] = *(const bh8*)(Alane + (size_t)t*16*(K) + (size_t)(kk)*16);

#define MFMA128(AF, CUR)                                                             \
    { bh8 bfx[4];                                                                    \
      _Pragma("unroll")                                                              \
      for(int t=0;t<4;t++)                                                           \
        bfx[t] = *(const bh8*)&lsB[CUR][(wn*64+t*16+l15)*32 + rsw*8];                \
      _Pragma("unroll")                                                              \
      for(int mt=0;mt<4;mt++)                                                        \
        _Pragma("unroll")                                                            \
        for(int nt=0;nt<4;nt++)                                                      \
          acc[mt][nt] = __builtin_amdgcn_mfma_f32_16x16x32_bf16(AF[mt], bfx[nt], acc[mt][nt], 0,0,0); }

// counted step: ages B(j)=2(old), A(j)=4, B(j+1)=2, A(j+1)=4 -> vmcnt(10) completes B(j).
#define CSTEP128(AFU, AFP, CUR, jj, Wb, K)                                           \
    if((jj)+1<NS){                                                                   \
      BSTAGE128(Wb, K, ((jj)+1)*32, (CUR)^1)                                         \
      asm volatile("" ::: "memory");                                                 \
      APREF4(AFP, K, ((jj)+1)*32)                                                    \
      asm volatile("s_waitcnt vmcnt(10)" ::: "memory");                              \
    } else {                                                                         \
      asm volatile("s_waitcnt vmcnt(0)" ::: "memory");                               \
    }                                                                                \
    __builtin_amdgcn_s_barrier();                                                    \
    MFMA128(AFU, CUR)                                                                \
    __builtin_amdgcn_s_barrier();

#define KLOOP_CNT128(Ab, Wb, K, WTILE)                                               \
  const int srow = w*32 + (lane>>2);                                                 \
  const int scol = (((lane&3) ^ ((srow>>1)&3)) * 8);                                 \
  const int rsw  = ((l15>>1)&3) ^ quad;                                              \
  const u16* Alane = (Ab) + (size_t)(WTILE)*16*(K) + lane*8;                         \
  bh8 afA[4], afB[4];                                                                \
  BSTAGE128(Wb, K, 0, 0)                                                             \
  asm volatile("" ::: "memory");                                                     \
  APREF4(afA, K, 0)                                                                  \
  const int NS = (K)>>5;                                                             \
  for(int j=0;j<NS;j+=2){                                                            \
    CSTEP128(afA, afB, 0, j,   Wb, K)                                                \
    CSTEP128(afB, afA, 1, j+1, Wb, K)                                                \
  }

// SYNC variant (proven best for the gelu up-proj): __syncthreads drains everything.
#define SSTEP128(AFU, AFP, CUR, jj, Wb, K)                                           \
    if((jj)+1<NS){                                                                   \
      BSTAGE128(Wb, K, ((jj)+1)*32, (CUR)^1)                                         \
      APREF4(AFP, K, ((jj)+1)*32)                                                    \
    }                                                                                \
    MFMA128(AFU, CUR)                                                                \
    __syncthreads();

#define KLOOP_SYNC128(Ab, Wb, K, WTILE)                                              \
  const int srow = w*32 + (lane>>2);                                                 \
  const int scol = (((lane&3) ^ ((srow>>1)&3)) * 8);                                 \
  const int rsw  = ((l15>>1)&3) ^ quad;                                              \
  const u16* Alane = (Ab) + (size_t)(WTILE)*16*(K) + lane*8;                         \
  bh8 afA[4], afB[4];                                                                \
  BSTAGE128(Wb, K, 0, 0)                                                             \
  APREF4(afA, K, 0)                                                                  \
  __syncthreads();                                                                   \
  const int NS = (K)>>5;                                                             \
  for(int j=0;j<NS;j+=2){                                                            \
    SSTEP128(afA, afB, 0, j,   Wb, K)                                                \
    SSTEP128(afB, afA, 1, j+1, Wb, K)                                                \
  }

// BN=64: 4 waves stacked in M (each 32 rows x 64 cols). B stage=1, A loads=2 -> vmcnt(5).
#define BSTAGE64(Wb, K, kk, buf)                                                     \
    async16(Wb + (size_t)browB*(K) + (kk) + scolB, &lsB[buf][(w*16)*32]);

#define APREF2(AF, K, kk)                                                            \
    _Pragma("unroll")                                                                \
    for(int t=0;t<2;t++)                                                             \
      AF[t] = *(const bh8*)(Alane + (size_t)t*16*(K) + (size_t)(kk)*16);

#define MFMA64(AF, CUR)                                                              \
    { bh8 bfx[4];                                                                    \
      _Pragma("unroll")                                                              \
      for(int t=0;t<4;t++)                                                           \
        bfx[t] = *(const bh8*)&lsB[CUR][(t*16+l15)*32 + rsw*8];                      \
      _Pragma("unroll")                                                              \
      for(int mt=0;mt<2;mt++)                                                        \
        _Pragma("unroll")                                                            \
        for(int nt=0;nt<4;nt++)                                                      \
          acc[mt][nt] = __builtin_amdgcn_mfma_f32_16x16x32_bf16(AF[mt], bfx[nt], acc[mt][nt], 0,0,0); }

#define CSTEP64(AFU, AFP, CUR, jj, Wb, K)                                            \
    if((jj)+1<NS){                                                                   \
      BSTAGE64(Wb, K, ((jj)+1)*32, (CUR)^1)                                          \
      asm volatile("" ::: "memory");                                                 \
      APREF2(AFP, K, ((jj)+1)*32)                                                    \
      asm volatile("s_waitcnt vmcnt(5)" ::: "memory");                               \
    } else {                                                                         \
      asm volatile("s_waitcnt vmcnt(0)" ::: "memory");                               \
    }                                                                                \
    __builtin_amdgcn_s_barrier();                                                    \
    MFMA64(AFU, CUR)                                                                 \
    __builtin_amdgcn_s_barrier();

#define KLOOP_CNT64(Ab, Wb, K)                                                       \
  const int browB = w*16 + (lane>>2);                                                \
  const int scolB = (((lane&3) ^ ((browB>>1)&3)) * 8);                               \
  const int rsw   = ((l15>>1)&3) ^ quad;                                             \
  const u16* Alane = (Ab) + (size_t)(w*2)*16*(K) + lane*8;                           \
  bh8 afA[2], afB[2];                                                                \
  BSTAGE64(Wb, K, 0, 0)                                                              \
  asm volatile("" ::: "memory");                                                     \
  APREF2(afA, K, 0)                                                                  \
  const int NS = (K)>>5;                                                             \
  for(int j=0;j<NS;j+=2){                                                            \
    CSTEP64(afA, afB, 0, j,   Wb, K)                                                 \
    CSTEP64(afB, afA, 1, j+1, Wb, K)                                                 \
  }

// ---------------- multi-output projection GEMM (BN=128, A frag-layout) ----------------
struct SubD { const float* bias; u16* out; float* ksum; int mode; };
struct Subs3 { SubD s[3]; };
__global__ __launch_bounds__(256) void gemm_qkv(const u16* __restrict__ A,
    const u16* __restrict__ W, Subs3 subs, int K, int wstride, int bstride, int ksstride){
  __shared__ __align__(16) u16 lsB[2][128*32];
  const int tid = threadIdx.x, lane = tid&63, w = tid>>6;
  const int quad = lane>>4, l15 = lane&15;
  const int2 swz = xcd_swz();
  const int bn = swz.x, bm = swz.y;
  const int iset = bm>>7;
  const int wm = w&1, wn = w>>1;
  fx4 acc[4][4];
  #pragma unroll
  for(int i=0;i<4;i++)
    #pragma unroll
    for(int j=0;j<4;j++) acc[i][j] = (fx4){0.f,0.f,0.f,0.f};
  const u16* Ab = A + (size_t)bm*128*K;      // == frag tile (bm*8) base
  const u16* Wb = W + (size_t)iset*wstride + (size_t)bn*128*K;
  KLOOP_CNT128(Ab, Wb, K, wm*4)
  const SubD sub = subs.s[bn>>2];
  const int colw = (bn&3)*128 + wn*64;
  const float* bias = sub.bias + iset*bstride;
  float bcol[4];
  #pragma unroll
  for(int nt=0;nt<4;nt++) bcol[nt] = bias[colw + nt*16 + l15];

  if(sub.mode==1){
    float ksacc[4] = {0.f,0.f,0.f,0.f};
    #pragma unroll
    for(int mt=0;mt<4;mt++)
      #pragma unroll
      for(int r=0;r<4;r++){
        float v0=acc[mt][0][r]+bcol[0], v1=acc[mt][1][r]+bcol[1];
        float v2=acc[mt][2][r]+bcol[2], v3=acc[mt][3][r]+bcol[3];
        float mx = fmaxf(fmaxf(v0,v1),fmaxf(v2,v3));
        mx = fmaxf(mx,__shfl_xor(mx,1,64)); mx = fmaxf(mx,__shfl_xor(mx,2,64));
        mx = fmaxf(mx,__shfl_xor(mx,4,64)); mx = fmaxf(mx,__shfl_xor(mx,8,64));
        float e0=__expf(v0-mx), e1=__expf(v1-mx), e2=__expf(v2-mx), e3=__expf(v3-mx);
        float s = e0+e1+e2+e3;
        s += __shfl_xor(s,1,64); s += __shfl_xor(s,2,64);
        s += __shfl_xor(s,4,64); s += __shfl_xor(s,8,64);
        float inv = __fdividef(1.f, s);
        e0*=inv; e1*=inv; e2*=inv; e3*=inv;
        ksacc[0]+=e0; ksacc[1]+=e1; ksacc[2]+=e2; ksacc[3]+=e3;
        int row = bm*128 + wm*64 + mt*16 + quad*4 + r;
        size_t rb = (size_t)row*512;
        sub.out[rb+colw+ 0+l15]=f2bf(e0); sub.out[rb+colw+16+l15]=f2bf(e1);
        sub.out[rb+colw+32+l15]=f2bf(e2); sub.out[rb+colw+48+l15]=f2bf(e3);
      }
    if(sub.ksum){
      int b = (bm&127)>>5;
      float* ks = sub.ksum + iset*ksstride + b*512;
      #pragma unroll
      for(int nt=0;nt<4;nt++){
        float s = ksacc[nt];
        s += __shfl_xor(s,16,64); s += __shfl_xor(s,32,64);
        if(quad==0) atomicAdd(&ks[colw + nt*16 + l15], s);
      }
    }
  } else {
    #pragma unroll
    for(int mt=0;mt<4;mt++)
      #pragma unroll
      for(int r=0;r<4;r++){
        int row = bm*128 + wm*64 + mt*16 + quad*4 + r;
        size_t rb = (size_t)row*512;
        #pragma unroll
        for(int nt=0;nt<4;nt++)
          sub.out[rb + colw + nt*16 + l15] = f2bf(acc[mt][nt][r] + bcol[nt]);
      }
  }
}

// ---------------- CA q-proj (BN=64): softmax epilogue, grid (8,128) ----------------
__global__ __launch_bounds__(256) void gemm_q64(const u16* __restrict__ A,
    const u16* __restrict__ W, const float* __restrict__ bias, u16* __restrict__ out){
  __shared__ __align__(16) u16 lsB[2][64*32];
  const int tid = threadIdx.x, lane = tid&63, w = tid>>6;
  const int quad = lane>>4, l15 = lane&15;
  const int2 swz = xcd_swz();
  const int bn = swz.x, bm = swz.y;
  fx4 acc[2][4];
  #pragma unroll
  for(int i=0;i<2;i++)
    #pragma unroll
    for(int j=0;j<4;j++) acc[i][j] = (fx4){0.f,0.f,0.f,0.f};
  const u16* Ab = A + (size_t)bm*128*512;
  const u16* Wb = W + (size_t)bn*64*512;
  KLOOP_CNT64(Ab, Wb, 512)
  const int colb = bn*64;
  float bcol[4];
  #pragma unroll
  for(int nt=0;nt<4;nt++) bcol[nt] = bias[colb + nt*16 + l15];
  #pragma unroll
  for(int mt=0;mt<2;mt++)
    #pragma unroll
    for(int r=0;r<4;r++){
      float v0=acc[mt][0][r]+bcol[0], v1=acc[mt][1][r]+bcol[1];
      float v2=acc[mt][2][r]+bcol[2], v3=acc[mt][3][r]+bcol[3];
      float mx = fmaxf(fmaxf(v0,v1),fmaxf(v2,v3));
      mx = fmaxf(mx,__shfl_xor(mx,1,64)); mx = fmaxf(mx,__shfl_xor(mx,2,64));
      mx = fmaxf(mx,__shfl_xor(mx,4,64)); mx = fmaxf(mx,__shfl_xor(mx,8,64));
      float e0=__expf(v0-mx), e1=__expf(v1-mx), e2=__expf(v2-mx), e3=__expf(v3-mx);
      float s = e0+e1+e2+e3;
      s += __shfl_xor(s,1,64); s += __shfl_xor(s,2,64);
      s += __shfl_xor(s,4,64); s += __shfl_xor(s,8,64);
      float inv = __fdividef(1.f, s);
      e0*=inv; e1*=inv; e2*=inv; e3*=inv;
      int row = bm*128 + w*32 + mt*16 + quad*4 + r;
      size_t rb = (size_t)row*512;
      out[rb+colb+ 0+l15]=f2bf(e0); out[rb+colb+16+l15]=f2bf(e1);
      out[rb+colb+32+l15]=f2bf(e2); out[rb+colb+48+l15]=f2bf(e3);
    }
}

// -------- out/down-proj (BN=64): C = A*W^T + bias + res -> fp32 row-major --------
__global__ __launch_bounds__(256) void gemm_dn64(const u16* __restrict__ A,
    const u16* __restrict__ W, const float* __restrict__ bias,
    const float* __restrict__ res, float* __restrict__ out, int N, int K){
  __shared__ __align__(16) u16 lsB[2][64*32];
  const int tid = threadIdx.x, lane = tid&63, w = tid>>6;
  const int quad = lane>>4, l15 = lane&15;
  const int2 swz = xcd_swz();
  const int bn = swz.x, bm = swz.y;
  fx4 acc[2][4];
  #pragma unroll
  for(int i=0;i<2;i++)
    #pragma unroll
    for(int j=0;j<4;j++) acc[i][j] = (fx4){0.f,0.f,0.f,0.f};
  const u16* Ab = A + (size_t)bm*128*K;
  const u16* Wb = W + (size_t)bn*64*K;
  KLOOP_CNT64(Ab, Wb, K)
  const int colb = bn*64;
  float bcol[4];
  #pragma unroll
  for(int nt=0;nt<4;nt++) bcol[nt] = bias[colb + nt*16 + l15];
  #pragma unroll
  for(int mt=0;mt<2;mt++)
    #pragma unroll
    for(int r=0;r<4;r++){
      int row = bm*128 + w*32 + mt*16 + quad*4 + r;
      size_t rb = (size_t)row*N;
      #pragma unroll
      for(int nt=0;nt<4;nt++){
        int col = colb + nt*16 + l15;
        out[rb+col] = res[rb+col] + acc[mt][nt][r] + bcol[nt];
      }
    }
}

// ------- FFN up-proj: C = A*W^T + bias -> gelu -> bf16 FRAGMENT layout (SYNC loop) -------
__global__ __launch_bounds__(256) void gemm_up(const u16* __restrict__ A,
    const u16* __restrict__ W, const float* __restrict__ bias,
    u16* __restrict__ out, int N, int K){
  __shared__ __align__(16) u16 lsB[2][128*32];
  const int tid = threadIdx.x, lane = tid&63, w = tid>>6;
  const int quad = lane>>4, l15 = lane&15;
  const int2 swz = xcd_swz();
  const int bn = swz.x, bm = swz.y;
  const int wm = w&1, wn = w>>1;
  fx4 acc[4][4];
  #pragma unroll
  for(int i=0;i<4;i++)
    #pragma unroll
    for(int j=0;j<4;j++) acc[i][j] = (fx4){0.f,0.f,0.f,0.f};
  const u16* Ab = A + (size_t)bm*128*K;
  const u16* Wb = W + (size_t)bn*128*K;
  KLOOP_SYNC128(Ab, Wb, K, wm*4)
  const int colbase = bn*128 + wn*64;
  float bcol[4];
  #pragma unroll
  for(int nt=0;nt<4;nt++) bcol[nt] = bias[colbase + nt*16 + l15];
  // frag-layout write, base hoisted: nt stride = (16 cols>>3)*128 = 256 u16.
  #pragma unroll
  for(int mt=0;mt<4;mt++)
    #pragma unroll
    for(int r=0;r<4;r++){
      int row = bm*128 + wm*64 + mt*16 + quad*4 + r;
      u16* ob = out + (size_t)(row>>4)*((size_t)N*16) + (size_t)(row&15)*8
              + (size_t)((colbase>>3) + (l15>>3))*128 + (l15&7);
      float g0 = gelu_fast(acc[mt][0][r] + bcol[0]);
      float g1 = gelu_fast(acc[mt][1][r] + bcol[1]);
      float g2 = gelu_fast(acc[mt][2][r] + bcol[2]);
      float g3 = gelu_fast(acc[mt][3][r] + bcol[3]);
      unsigned p01 = cvtpk(g0,g1), p23 = cvtpk(g2,g3);
      ob[0]   = (u16)p01; ob[256] = (u16)(p01>>16);
      ob[512] = (u16)p23; ob[768] = (u16)(p23>>16);
    }
}

// ---------------- ctx[i,b,h][d1][d2] = sum_t k[t][d1] v[t][d2] (MFMA over t) ----------------
__global__ __launch_bounds__(256) void ctx_kernel(const u16* __restrict__ kb,
    const u16* __restrict__ vb, float* __restrict__ ctx, size_t kstride){
  __shared__ __align__(16) u16 lk[64*72];  // transposed [d][t], stride 72
  __shared__ __align__(16) u16 lv[64*72];
  const int tid=threadIdx.x, lane=tid&63, w=tid>>6, quad=lane>>4, l15=lane&15;
  const int bh2 = blockIdx.x, i = bh2>>5, h = bh2&7, b = (bh2>>3)&3;
  const u16* kbase = kb + (size_t)i*kstride;
  const u16* vbase = vb + (size_t)i*kstride;
  const size_t rowbase = (size_t)b*4096 + (size_t)blockIdx.y*512;
  const int mt0=(w&1)*32, nt0=(w>>1)*32;
  fx4 acc[2][2];
  #pragma unroll
  for(int x=0;x<2;x++)
    #pragma unroll
    for(int j=0;j<2;j++) acc[x][j] = (fx4){0.f,0.f,0.f,0.f};
  const int tl = tid>>2, part = tid&3;
  for(int it=0; it<8; it++){
    __syncthreads();
    {
      size_t gro = (rowbase + it*64 + tl)*512 + h*64 + part*16;
      bh8 k0 = *(const bh8*)(kbase + gro); bh8 k1 = *(const bh8*)(kbase + gro + 8);
      bh8 v0 = *(const bh8*)(vbase + gro); bh8 v1 = *(const bh8*)(vbase + gro + 8);
      #pragma unroll
      for(int j=0;j<8;j++){
        lk[(part*16+j  )*72 + tl] = (u16)k0[j];
        lk[(part*16+8+j)*72 + tl] = (u16)k1[j];
        lv[(part*16+j  )*72 + tl] = (u16)v0[j];
        lv[(part*16+8+j)*72 + tl] = (u16)v1[j];
      }
    }
    __syncthreads();
    #pragma unroll
    for(int ks=0;ks<2;ks++){
      bh8 a0 = *(const bh8*)&lk[(mt0    +l15)*72 + ks*32 + quad*8];
      bh8 a1 = *(const bh8*)&lk[(mt0+16 +l15)*72 + ks*32 + quad*8];
      bh8 b0 = *(const bh8*)&lv[(nt0    +l15)*72 + ks*32 + quad*8];
      bh8 b1 = *(const bh8*)&lv[(nt0+16 +l15)*72 + ks*32 + quad*8];
      acc[0][0] = __builtin_amdgcn_mfma_f32_16x16x32_bf16(a0,b0,acc[0][0],0,0,0);
      acc[0][1] = __builtin_amdgcn_mfma_f32_16x16x32_bf16(a0,b1,acc[0][1],0,0,0);
      acc[1][0] = __builtin_amdgcn_mfma_f32_16x16x32_bf16(a1,b0,acc[1][0],0,0,0);
      acc[1][1] = __builtin_amdgcn_mfma_f32_16x16x32_bf16(a1,b1,acc[1][1],0,0,0);
    }
  }
  float* cb = ctx + (size_t)bh2*4096;
  #pragma unroll
  for(int mi=0;mi<2;mi++)
    #pragma unroll
    for(int ni=0;ni<2;ni++)
      #pragma unroll
      for(int r=0;r<4;r++){
        int d1 = mt0 + mi*16 + quad*4 + r;
        int d2 = nt0 + ni*16 + l15;
        atomicAdd(&cb[d1*64 + d2], acc[mi][ni][r]);
      }
}

// --- out = q + sum_i (q @ ctx_i)*Dinv_i; writes OUTB in FRAGMENT layout (K=512) ---
template<int NIN>
__global__ __launch_bounds__(256) void apply_kernel(const u16* __restrict__ q,
    const float* __restrict__ ctx, const float* __restrict__ ksum, float eps,
    u16* __restrict__ out){
  __shared__ __align__(16) u16 lctx[(NIN+1)*64*72];
  const int tid=threadIdx.x, lane=tid&63, w=tid>>6, quad=lane>>4, l15=lane&15;
  const int bh = blockIdx.x, b=bh>>3, h=bh&7;
  {
    int base = tid*16;
    int d1 = base>>6, d2b = base&63;
    #pragma unroll
    for(int s=0;s<=NIN;s++){
      u16* dst = &lctx[s*64*72];
      if(s<NIN){
        const float* sp = ctx + ((size_t)s*32 + bh)*4096 + base;
        #pragma unroll
        for(int j=0;j<16;j++) dst[(d2b+j)*72 + d1] = f2bf(sp[j]);
      } else {
        #pragma unroll
        for(int j=0;j<16;j++) dst[(d2b+j)*72 + d1] = ((d2b+j)==d1) ? (u16)0x3f80 : (u16)0;
      }
    }
  }
  float kslo[NIN][8], kshi[NIN][8];
  #pragma unroll
  for(int s=0;s<NIN;s++){
    const float* ks = ksum + s*2048 + b*512 + h*64;
    #pragma unroll
    for(int j=0;j<8;j++){ kslo[s][j] = ks[quad*8+j]; kshi[s][j] = ks[32+quad*8+j]; }
  }
  __syncthreads();
  bh8 bfr[NIN+1][4][2];
  #pragma unroll
  for(int s=0;s<=NIN;s++)
    #pragma unroll
    for(int nt=0;nt<4;nt++)
      #pragma unroll
      for(int ks=0;ks<2;ks++)
        bfr[s][nt][ks] = *(const bh8*)&lctx[s*64*72 + (nt*16+l15)*72 + ks*32 + quad*8];
  const size_t tb0 = (size_t)b*4096 + (size_t)blockIdx.y*256 + w*64;
  for(int g=0;g<4;g++){
    size_t tb = tb0 + g*16;
    const u16* qr = q + (tb + l15)*512 + h*64;
    bh8 a0 = *(const bh8*)(qr + quad*8);
    bh8 a1 = *(const bh8*)(qr + 32 + quad*8);
    float dv[NIN][4];
    #pragma unroll
    for(int s=0;s<NIN;s++){
      float part = 0.f;
      #pragma unroll
      for(int j=0;j<8;j++)
        part += bf2f((u16)a0[j])*kslo[s][j] + bf2f((u16)a1[j])*kshi[s][j];
      part += __shfl_xor(part,16,64); part += __shfl_xor(part,32,64);
      #pragma unroll
      for(int r=0;r<4;r++)
        dv[s][r] = __fdividef(1.f, __shfl(part, quad*4+r, 64) + eps);
    }
    fx4 outv[4];
    #pragma unroll
    for(int nt=0;nt<4;nt++) outv[nt] = (fx4){0.f,0.f,0.f,0.f};
    #pragma unroll
    for(int s=0;s<=NIN;s++){
      fx4 c[4];
      #pragma unroll
      for(int nt=0;nt<4;nt++){
        c[nt] = (fx4){0.f,0.f,0.f,0.f};
        c[nt] = __builtin_amdgcn_mfma_f32_16x16x32_bf16(a0, bfr[s][nt][0], c[nt], 0,0,0);
        c[nt] = __builtin_amdgcn_mfma_f32_16x16x32_bf16(a1, bfr[s][nt][1], c[nt], 0,0,0);
      }
      #pragma unroll
      for(int nt=0;nt<4;nt++)
        #pragma unroll
        for(int r=0;r<4;r++) outv[nt][r] += c[nt][r]*((s==NIN)?1.f:dv[s][r]);
    }
    #pragma unroll
    for(int nt=0;nt<4;nt++)
      #pragma unroll
      for(int r=0;r<4;r++)
        out[faddr((int)tb + quad*4 + r, h*64 + nt*16 + l15, 512)] = f2bf(outv[nt][r]);
  }
}

// =========================================================================
extern "C" void kernel_launch(void* const* d_in, const int* in_sizes, int n_in,
                              void* d_out, int out_size, void* d_ws, size_t ws_size,
                              hipStream_t stream){
  const float* x_in =(const float*)d_in[0];
  const float* ys   =(const float*)d_in[1];
  const float* ln1g =(const float*)d_in[2],  *ln1b=(const float*)d_in[3];
  const float* ln2g =(const float*)d_in[4],  *ln2b=(const float*)d_in[5];
  const float* ln3g =(const float*)d_in[6],  *ln3b=(const float*)d_in[7];
  const float* ln4g =(const float*)d_in[8],  *ln4b=(const float*)d_in[9];
  const float* ln5g =(const float*)d_in[10], *ln5b=(const float*)d_in[11];
  const float* ca_wq=(const float*)d_in[12], *ca_bq=(const float*)d_in[13];
  const float* ca_wk=(const float*)d_in[14], *ca_bk=(const float*)d_in[15];
  const float* ca_wv=(const float*)d_in[16], *ca_bv=(const float*)d_in[17];
  const float* ca_wo=(const float*)d_in[18], *ca_bo=(const float*)d_in[19];
  const float* sa_wq=(const float*)d_in[20], *sa_bq=(const float*)d_in[21];
  const float* sa_wk=(const float*)d_in[22], *sa_bk=(const float*)d_in[23];
  const float* sa_wv=(const float*)d_in[24], *sa_bv=(const float*)d_in[25];
  const float* sa_wo=(const float*)d_in[26], *sa_bo=(const float*)d_in[27];
  const float* f1w1 =(const float*)d_in[28], *f1b1=(const float*)d_in[29];
  const float* f1w2 =(const float*)d_in[30], *f1b2=(const float*)d_in[31];
  const float* f2w1 =(const float*)d_in[32], *f2b1=(const float*)d_in[33];
  const float* f2w2 =(const float*)d_in[34], *f2b2=(const float*)d_in[35];

  char* p = (char*)d_ws;
  u16*   WBF = (u16*)p;    p += 13631488;   // bf16 weights (row-major)
  float* XW  = (float*)p;  p += 33554432;   // residual stream fp32 [16384,512]
  u16*   XN2 = (u16*)p;    p += 33554432;   // LN out (frag layout), up to 2x16384 rows
  u16*   QB  = (u16*)p;    p += 16777216;   // q softmax out (row-major)
  u16*   R1  = (u16*)p;    p += 67108864;   // FFN hidden (frag) OR stacked KB2|VB2 (row)
  u16*   OUTB= (u16*)p;    p += 16777216;   // attn out / x-LN staging (frag layout)
  float* SM  = (float*)p;  p += 1597440;    // ctx + ksum (zeroed)
  u16*   XN  = XN2;
  u16*   KB2 = R1;
  u16*   VB2 = R1 + 16777216;
  u16*   HB  = R1;
  float* CTXC = SM;                          // [2][32][4096]
  float* CTXS = SM + 262144;                 // [32][4096]
  float* KSC  = SM + 393216;                 // [2][4][512]
  float* KSS  = SM + 397312;                 // [4][512]

  WDesc wd;
  const float* wsrc[14] = {ca_wq, ca_wk, ca_wv, ca_wk+262144, ca_wv+262144, ca_wo,
                           sa_wq, sa_wk, sa_wv, sa_wo, f1w1, f1w2, f2w1, f2w2};
  const int    woff[14] = {0, 262144, 524288, 786432, 1048576, 1310720,
                           1572864, 1835008, 2097152, 2359296,
                           2621440, 3670016, 4718592, 5767168};
  for(int i=0;i<14;i++){ wd.src[i]=wsrc[i]; wd.off[i]=woff[i]; }
  convw_kernel<<<26624,256,0,stream>>>(wd, WBF);
  hipMemsetAsync(SM, 0, 399360*sizeof(float), stream);

  SubD zsub = {nullptr,nullptr,nullptr,0};

  // ---- cross attention ----
  ln_kernel<<<4096,256,0,stream>>>(x_in, ln1g, ln1b, OUTB);   // x-LN staged (frag) in OUTB
  lny_kernel<<<8192,256,0,stream>>>(ys, ln2g, ln2b, XN2);     // both ys LNs (frag)
  gemm_q64<<<dim3(8,128),256,0,stream>>>(OUTB, WBF+0, ca_bq, QB);
  { Subs3 s = {{ {ca_bk, KB2, KSC, 1}, {ca_bv, VB2, nullptr, 0}, zsub }};
    gemm_qkv<<<dim3(8,256),256,0,stream>>>(XN2, WBF+262144, s, 512,
                                           524288, 512, 2048); }  // i = bm>>7
  ctx_kernel<<<dim3(64,8),256,0,stream>>>(KB2, VB2, CTXC, (size_t)16384*512);
  apply_kernel<2><<<dim3(32,16),256,0,stream>>>(QB, CTXC, KSC, 1e-8f, OUTB);
  gemm_dn64<<<dim3(8,128),256,0,stream>>>(OUTB, WBF+1310720, ca_bo, x_in, XW, 512, 512);

  // ---- FFN 1 ----
  ln_kernel<<<4096,256,0,stream>>>(XW, ln3g, ln3b, XN);
  gemm_up<<<dim3(16,128),256,0,stream>>>(XN, WBF+2621440, f1b1, HB, 2048, 512);
  gemm_dn64<<<dim3(8,128),256,0,stream>>>(HB, WBF+3670016, f1b2, XW, XW, 512, 2048);

  // ---- linear self attention ----
  ln_kernel<<<4096,256,0,stream>>>(XW, ln4g, ln4b, XN);
  { Subs3 s = {{ {sa_bq, QB, nullptr, 1}, {sa_bk, KB2, KSS, 1}, {sa_bv, VB2, nullptr, 0} }};
    gemm_qkv<<<dim3(12,128),256,0,stream>>>(XN, WBF+1572864, s, 512, 0,0,0); }
  ctx_kernel<<<dim3(32,8),256,0,stream>>>(KB2, VB2, CTXS, 0);
  apply_kernel<1><<<dim3(32,16),256,0,stream>>>(QB, CTXS, KSS, 0.f, OUTB);
  gemm_dn64<<<dim3(8,128),256,0,stream>>>(OUTB, WBF+2359296, sa_bo, XW, XW, 512, 512);

  // ---- FFN 2 ----
  ln_kernel<<<4096,256,0,stream>>>(XW, ln5g, ln5b, XN);
  gemm_up<<<dim3(16,128),256,0,stream>>>(XN, WBF+4718592, f2b1, HB, 2048, 512);
  gemm_dn64<<<dim3(8,128),256,0,stream>>>(HB, WBF+5767168, f2b2, XW, (float*)d_out, 512, 2048);
}